// Round 2
// baseline (1701.673 us; speedup 1.0000x reference)
//
#include <hip/hip_runtime.h>
#include <hip/hip_bf16.h>

// Decoder (EGNN) on MI355X. pos==0 identity => stage-2/pos/counts dead.
// ROUND 1: launch-gap theory. 14 dispatches -> memset + ONE persistent kernel
// (512 blocks x 256 thr = exactly 2 blocks/CU co-resident; manual device-scope
// generation barrier). Phases:
//   ph0: An=(nf@Wn+bn)@eW1 (bids 0-63) | g=z@Wg+bg (64) | wfrag (66-69) |
//        count (72-199, cntI pre-zeroed by memset)
//   ph1: scan+items (bid 0) | Ag=g@eW1 (bid 1)
//   ph2: bucket (all, 64 edges each) + pre1 materialize h/A1t/A2bf (all)
//   4x { edge (wave work-steal over 16-edge chunks, MFMA) | bar |
//        post (bids 0-255, 4x4 reg tiles, transposed XT) | bar }
// Barrier: acq-rel atomics at AGENT scope + __threadfence (L2 wb/inv for
// cross-XCD visibility of P / A1t / A2bf).

namespace {

constexpr int kB = 16, kN = 1024, kH = 64, kE = 32768, kLat = 128;
constexpr int kC = 16;                 // edges per wave-chunk
constexpr int kMaxItems = 3200;        // >= sum ceil(deg/16) (~2510)
constexpr int NBLK = 512;              // 2 blocks/CU, co-resident by construction

typedef __attribute__((ext_vector_type(8))) short short8;   // 8 bf16
typedef __attribute__((ext_vector_type(4))) float floatx4;

__device__ __forceinline__ unsigned short f2bf(float f){   // RNE
  union { float f; unsigned int u; } v; v.f = f;
  unsigned int r = v.u + 0x7fffu + ((v.u >> 16) & 1u);
  return (unsigned short)(r >> 16);
}
__device__ __forceinline__ unsigned int packbf(float a, float b){
  return ((unsigned int)f2bf(b) << 16) | (unsigned int)f2bf(a);
}
__device__ __forceinline__ unsigned int pack2f(float a, float b){ // fast half-up
  unsigned int ua = __float_as_uint(a) + 0x8000u;
  unsigned int ub = __float_as_uint(b) + 0x8000u;
  return __builtin_amdgcn_perm(ub, ua, 0x07060302);
}
__device__ __forceinline__ float bflo(unsigned int u){
  union { unsigned int u; float f; } v; v.u = u << 16; return v.f;
}
__device__ __forceinline__ float bfhi(unsigned int u){
  union { unsigned int u; float f; } v; v.u = u & 0xffff0000u; return v.f;
}
__device__ __forceinline__ float silu2(float x){   // 2 trans + 3 alu
  float u = __builtin_amdgcn_exp2f(-1.44269504f * x);
  return x * __builtin_amdgcn_rcpf(1.0f + u);
}

// Generation-counter grid barrier. Safe: bar reset happens-before gen bump
// (release), so next-barrier arrivals (after acquire of gen) can't race the
// reset. threadfence = agent fence -> L2 writeback + invalidate (cross-XCD).
__device__ __forceinline__ void gridbar(int* bar, int* gen){
  __syncthreads();
  if (threadIdx.x == 0){
    __threadfence();
    int g = __hip_atomic_load(gen, __ATOMIC_RELAXED, __HIP_MEMORY_SCOPE_AGENT);
    int a = __hip_atomic_fetch_add(bar, 1, __ATOMIC_ACQ_REL, __HIP_MEMORY_SCOPE_AGENT);
    if (a == NBLK - 1){
      __hip_atomic_store(bar, 0, __ATOMIC_RELAXED, __HIP_MEMORY_SCOPE_AGENT);
      __hip_atomic_fetch_add(gen, 1, __ATOMIC_ACQ_REL, __HIP_MEMORY_SCOPE_AGENT);
    } else {
      while (__hip_atomic_load(gen, __ATOMIC_ACQUIRE, __HIP_MEMORY_SCOPE_AGENT) == g)
        __builtin_amdgcn_s_sleep(4);
    }
    __threadfence();
  }
  __syncthreads();
}

__global__ __launch_bounds__(256, 2) void k_all(
    const float* z, const int* ei, const float* nf,
    const float* Wg, const float* bg, const float* Wn, const float* bn,
    const float* eW1, const float* eb1_, const float* eW2, const float* eb2,
    const float* nW1, const float* nb1_, const float* nW2, const float* nb2_,
    const float* lng_, const float* lnb_,
    const float* oW1, const float* ob1_, const float* oW2, const float* ob2_,
    float* h, float* A1t, unsigned short* A2bf, unsigned short* wfragE,
    float* P, float* g, float* An1, float* An2, float* Ag1, float* Ag2,
    int* cntI, int* fill, int* ctrl, int* off, int* ioff, int* items,
    int* nitems, int* ecol, float* out){
  __shared__ __align__(16) float SM[9280];   // union: An W0|W1|HR ; post W|XT ; scan s0|s1
  __shared__ float b1s[64], b2s[64], lgs[64], lbs[64];
  __shared__ float W2o[192];
  __shared__ float ob2s[4];
  int tid = threadIdx.x, bid = blockIdx.x;
  int* bar = ctrl; int* gen = ctrl + 1; int* wsteal = ctrl + 2;

  // ================= ph0 =================
  if (bid < 64){                      // An1/An2 = (nf@Wn+bn) @ eW1[0]
    float* W0 = SM; float* W1 = SM + 4096; float* HR = SM + 8192;
    const float4* e1a = (const float4*)(eW1);
    const float4* e1b = (const float4*)(eW1 + 4096);
    for (int i = tid; i < 1024; i += 256){
      ((float4*)W0)[i] = e1a[i]; ((float4*)W1)[i] = e1b[i];
    }
    int rl = tid >> 4, c = tid & 15, j0 = c*4;
    int n = bid*16 + rl;
    float f0 = nf[n*3], f1 = nf[n*3+1], f2 = nf[n*3+2];
    float4 hv;
    hv.x = f0*Wn[j0+0] + f1*Wn[64+j0+0] + f2*Wn[128+j0+0] + bn[j0+0];
    hv.y = f0*Wn[j0+1] + f1*Wn[64+j0+1] + f2*Wn[128+j0+1] + bn[j0+1];
    hv.z = f0*Wn[j0+2] + f1*Wn[64+j0+2] + f2*Wn[128+j0+2] + bn[j0+2];
    hv.w = f0*Wn[j0+3] + f1*Wn[64+j0+3] + f2*Wn[128+j0+3] + bn[j0+3];
    *(float4*)(HR + rl*68 + j0) = hv;
    __syncthreads();
    float4 b1 = *(const float4*)(eb1_ + j0);
    float a1[4] = { b1.x, b1.y, b1.z, b1.w };
    float a2[4] = { 0.f, 0.f, 0.f, 0.f };
    #pragma unroll 8
    for (int k = 0; k < 64; k++){
      float hk = HR[rl*68 + k];
      float4 w1 = *(const float4*)(W0 + k*64 + j0);
      float4 w2 = *(const float4*)(W1 + k*64 + j0);
      a1[0] += hk*w1.x; a1[1] += hk*w1.y; a1[2] += hk*w1.z; a1[3] += hk*w1.w;
      a2[0] += hk*w2.x; a2[1] += hk*w2.y; a2[2] += hk*w2.z; a2[3] += hk*w2.w;
    }
    float4 o1 = { a1[0], a1[1], a1[2], a1[3] };
    float4 o2 = { a2[0], a2[1], a2[2], a2[3] };
    *(float4*)(An1 + n*64 + j0) = o1;
    *(float4*)(An2 + n*64 + j0) = o2;
  } else if (bid == 64){              // g = z @ Wg + bg
    int bb = tid >> 4, j0 = (tid & 15)*4;
    float4 acc = *(const float4*)(bg + j0);
    for (int k = 0; k < kLat; k++){
      float zk = z[bb*kLat + k];
      float4 w = *(const float4*)(Wg + k*64 + j0);
      acc.x += zk*w.x; acc.y += zk*w.y; acc.z += zk*w.z; acc.w += zk*w.w;
    }
    *(float4*)(g + bb*64 + j0) = acc;
  } else if (bid >= 66 && bid < 70){  // wfrag (MFMA A-fragments of eW2)
    int l = bid - 66;
    for (int i = tid; i < 4096; i += 256){
      int f = i >> 9, lane = (i >> 3) & 63, j8 = i & 7;
      int jt = f >> 1, ks = f & 1;
      int k = ks*32 + (lane >> 4)*8 + j8;
      int j = jt*16 + (lane & 15);
      wfragE[l*4096 + i] = f2bf(eW2[l*4096 + k*64 + j]);
    }
  } else if (bid >= 72 && bid < 200){ // count (cntI zeroed by memset)
    int e = (bid - 72)*256 + tid;
    atomicAdd(&cntI[ei[e]], 1);
  }
  gridbar(bar, gen);

  // ================= ph1 =================
  if (bid == 0){                      // scan: off, ioff, items, nitems
    int* s0 = (int*)SM; int* s1 = s0 + 1024;
    for (int i = tid; i < 1024; i += 256) s0[i] = cntI[i];
    __syncthreads();
    int* src = s0; int* dst = s1;
    for (int o = 1; o < 1024; o <<= 1){
      for (int i = tid; i < 1024; i += 256)
        dst[i] = src[i] + ((i >= o) ? src[i-o] : 0);
      __syncthreads();
      int* t_ = src; src = dst; dst = t_;
    }
    for (int i = tid; i < 1024; i += 256) off[i] = src[i] - cntI[i];
    if (tid == 0) off[1024] = src[1023];
    __syncthreads();
    for (int i = tid; i < 1024; i += 256) dst[i] = (cntI[i] + (kC-1))/kC;
    __syncthreads();
    int* src2 = dst; int* dst2 = src;
    for (int o = 1; o < 1024; o <<= 1){
      for (int i = tid; i < 1024; i += 256)
        dst2[i] = src2[i] + ((i >= o) ? src2[i-o] : 0);
      __syncthreads();
      int* t_ = src2; src2 = dst2; dst2 = t_;
    }
    for (int i = tid; i < 1024; i += 256){
      int ic = (cntI[i] + (kC-1))/kC;
      int ib = src2[i] - ic;
      ioff[i] = ib;
      for (int s = 0; s < ic; s++) items[ib + s] = (i << 12) | s;
    }
    if (tid == 0){ ioff[1024] = src2[1023]; *nitems = src2[1023]; }
  } else if (bid == 1){               // Ag1/Ag2 = g @ eW1[0]
    int bb = tid >> 4, j0 = (tid & 15)*4;
    float a1[4] = {0.f,0.f,0.f,0.f}, a2[4] = {0.f,0.f,0.f,0.f};
    for (int k = 0; k < 64; k++){
      float gk = g[bb*64 + k];
      float4 w1 = *(const float4*)(eW1 + k*64 + j0);
      float4 w2 = *(const float4*)(eW1 + 4096 + k*64 + j0);
      a1[0] += gk*w1.x; a1[1] += gk*w1.y; a1[2] += gk*w1.z; a1[3] += gk*w1.w;
      a2[0] += gk*w2.x; a2[1] += gk*w2.y; a2[2] += gk*w2.z; a2[3] += gk*w2.w;
    }
    float4 o1 = { a1[0], a1[1], a1[2], a1[3] };
    float4 o2 = { a2[0], a2[1], a2[2], a2[3] };
    *(float4*)(Ag1 + bb*64 + j0) = o1;
    *(float4*)(Ag2 + bb*64 + j0) = o2;
  }
  gridbar(bar, gen);

  // ================= ph2: bucket + pre1 =================
  if (tid < 64){
    int e = bid*64 + tid;
    int r = ei[e];
    int s = atomicAdd(&fill[r], 1);
    ecol[off[r] + s] = ei[kE + e];
  }
  #pragma unroll
  for (int u = 0; u < 2; u++){
    int idx = bid*512 + u*256 + tid;
    int row = idx >> 4;              // n*16 + bb
    int j0  = (idx & 15) * 4;
    int n = row >> 4, bb = row & 15;
    float4 a1 = *(const float4*)(An1 + n*64 + j0);
    float4 g1 = *(const float4*)(Ag1 + bb*64 + j0);
    a1.x += g1.x; a1.y += g1.y; a1.z += g1.z; a1.w += g1.w;
    *(float4*)(A1t + row*64 + j0) = a1;
    float4 a2 = *(const float4*)(An2 + n*64 + j0);
    float4 g2 = *(const float4*)(Ag2 + bb*64 + j0);
    a2.x += g2.x; a2.y += g2.y; a2.z += g2.z; a2.w += g2.w;
    uint2 pk; pk.x = packbf(a2.x, a2.y); pk.y = packbf(a2.z, a2.w);
    *(uint2*)(A2bf + row*64 + j0) = pk;
    float f0 = nf[n*3], f1 = nf[n*3+1], f2 = nf[n*3+2];
    float4 w0 = *(const float4*)(Wn + j0);
    float4 w1 = *(const float4*)(Wn + 64 + j0);
    float4 w2 = *(const float4*)(Wn + 128 + j0);
    float4 bv = *(const float4*)(bn + j0);
    float4 gv = *(const float4*)(g + bb*64 + j0);
    float4 hv;
    hv.x = f0*w0.x + f1*w1.x + f2*w2.x + bv.x + gv.x;
    hv.y = f0*w0.y + f1*w1.y + f2*w2.y + bv.y + gv.y;
    hv.z = f0*w0.z + f1*w1.z + f2*w2.z + bv.z + gv.z;
    hv.w = f0*w0.w + f1*w1.w + f2*w2.w + bv.w + gv.w;
    *(float4*)(h + (bb*1024 + n)*64 + j0) = hv;
  }
  gridbar(bar, gen);

  int nit = *nitems;
  int lane = tid & 63, m = lane & 15, quad = lane >> 4;

  for (int l = 0; l < 4; l++){
    // ---------------- edge: wave work-steal over chunks ----------------
    short8 wf[8];
    #pragma unroll
    for (int f = 0; f < 8; f++)
      wf[f] = *(const short8*)(wfragE + l*4096 + f*512 + lane*8);
    for (;;){
      int w = 0;
      if (lane == 0) w = atomicAdd(&wsteal[l], 1);
      w = __shfl(w, 0, 64);
      if (w >= nit) break;
      int it = items[w];
      int r = it >> 12, s = it & 4095;
      int e0 = off[r] + s*kC;
      int e1 = min(off[r+1], e0 + kC);
      float4 a1[4];
      #pragma unroll
      for (int ks = 0; ks < 2; ks++){
        a1[ks*2+0] = *(const float4*)(A1t + (r<<10) + (m<<6) + ks*32 + quad*8);
        a1[ks*2+1] = *(const float4*)(A1t + (r<<10) + (m<<6) + ks*32 + quad*8 + 4);
      }
      floatx4 dini[4], agg[4];
      #pragma unroll
      for (int jt = 0; jt < 4; jt++){
        dini[jt] = *(const floatx4*)(eb2 + l*64 + jt*16 + quad*4);
        agg[jt] = (floatx4){0.f,0.f,0.f,0.f};
      }
      int c0 = ecol[e0];
      uint4 p0 = *(const uint4*)(A2bf + ((c0<<4)+m)*64 + quad*8);
      uint4 p1 = *(const uint4*)(A2bf + ((c0<<4)+m)*64 + 32 + quad*8);
      for (int e = e0; e < e1; e++){
        uint4 c_0 = p0, c_1 = p1;
        if (e + 1 < e1){
          int cn = ecol[e+1];
          p0 = *(const uint4*)(A2bf + ((cn<<4)+m)*64 + quad*8);
          p1 = *(const uint4*)(A2bf + ((cn<<4)+m)*64 + 32 + quad*8);
        }
        short8 bfr[2];
        #pragma unroll
        for (int ks = 0; ks < 2; ks++){
          uint4 a2r = (ks == 0) ? c_0 : c_1;
          float4 x0 = a1[ks*2+0];
          float4 x1 = a1[ks*2+1];
          float v0 = silu2(x0.x + bflo(a2r.x));
          float v1 = silu2(x0.y + bfhi(a2r.x));
          float v2 = silu2(x0.z + bflo(a2r.y));
          float v3 = silu2(x0.w + bfhi(a2r.y));
          float v4 = silu2(x1.x + bflo(a2r.z));
          float v5 = silu2(x1.y + bfhi(a2r.z));
          float v6 = silu2(x1.z + bflo(a2r.w));
          float v7 = silu2(x1.w + bfhi(a2r.w));
          union { uint4 u; short8 s; } bu;
          bu.u.x = pack2f(v0, v1); bu.u.y = pack2f(v2, v3);
          bu.u.z = pack2f(v4, v5); bu.u.w = pack2f(v6, v7);
          bfr[ks] = bu.s;
        }
        #pragma unroll
        for (int jt = 0; jt < 4; jt++){
          floatx4 d = dini[jt];
          d = __builtin_amdgcn_mfma_f32_16x16x32_bf16(wf[jt*2+0], bfr[0], d, 0, 0, 0);
          d = __builtin_amdgcn_mfma_f32_16x16x32_bf16(wf[jt*2+1], bfr[1], d, 0, 0, 0);
          floatx4 a = agg[jt];
          a.x += silu2(d.x); a.y += silu2(d.y);
          a.z += silu2(d.z); a.w += silu2(d.w);
          agg[jt] = a;
        }
      }
      #pragma unroll
      for (int jt = 0; jt < 4; jt++)
        *(floatx4*)(P + w*1024 + m*64 + jt*16 + quad*4) = agg[jt];
    }
    gridbar(bar, gen);

    // ---------------- post: bids 0..255 (64 rows, 4x4 reg tiles) -------
    if (bid < 256){
      bool last = (l == 3);
      float* Wl = SM; float* XT = SM + 4096;     // XT stride 68
      int bb = bid >> 4;
      int n0 = (bid & 15) * 64;
      int c = tid & 15, gq = tid >> 4;
      int j0 = c*4, r0 = gq*4;
      int rowbase = bb*1024 + n0 + r0;

      { const float4* p1 = (const float4*)(nW1 + l*8192);
        float4* d = (float4*)Wl;
        d[tid] = p1[tid]; d[tid+256] = p1[tid+256];
        d[tid+512] = p1[tid+512]; d[tid+768] = p1[tid+768]; }
      float hold[4][4];
      #pragma unroll
      for (int i = 0; i < 4; i++){
        float4 v = *(const float4*)(h + (rowbase + i)*64 + j0);
        hold[i][0]=v.x; hold[i][1]=v.y; hold[i][2]=v.z; hold[i][3]=v.w;
      }
      #pragma unroll
      for (int j = 0; j < 4; j++){
        float4 t = { hold[0][j], hold[1][j], hold[2][j], hold[3][j] };
        *(float4*)(XT + (j0 + j)*68 + r0) = t;
      }
      float acc[4][4];
      { float4 b1 = *(const float4*)(nb1_ + l*64 + j0);
        float bv[4] = { b1.x, b1.y, b1.z, b1.w };
        #pragma unroll
        for (int i = 0; i < 4; i++)
          #pragma unroll
          for (int j = 0; j < 4; j++) acc[i][j] = bv[j]; }
      __syncthreads();
      #pragma unroll 4
      for (int k = 0; k < 64; k++){            // t += h @ nW1lo
        float4 w = *(const float4*)(Wl + k*64 + j0);
        float4 x = *(const float4*)(XT + k*68 + r0);
        float xv[4] = { x.x, x.y, x.z, x.w };
        float wv[4] = { w.x, w.y, w.z, w.w };
        #pragma unroll
        for (int i = 0; i < 4; i++)
          #pragma unroll
          for (int j = 0; j < 4; j++) acc[i][j] += xv[i]*wv[j];
      }
      __syncthreads();
      { const float4* p2 = (const float4*)(nW1 + l*8192 + 4096);
        float4* d = (float4*)Wl;
        d[tid] = p2[tid]; d[tid+256] = p2[tid+256];
        d[tid+512] = p2[tid+512]; d[tid+768] = p2[tid+768]; }
      { float agt[4][4];
        #pragma unroll
        for (int i = 0; i < 4; i++){
          int n = n0 + r0 + i;
          float4 s = { 0.f, 0.f, 0.f, 0.f };
          int i0 = ioff[n], i1 = ioff[n+1];
          for (int it = i0; it < i1; it++){
            float4 v = *(const float4*)(P + it*1024 + bb*64 + j0);
            s.x += v.x; s.y += v.y; s.z += v.z; s.w += v.w;
          }
          agt[i][0]=s.x; agt[i][1]=s.y; agt[i][2]=s.z; agt[i][3]=s.w;
        }
        #pragma unroll
        for (int j = 0; j < 4; j++){
          float4 t = { agt[0][j], agt[1][j], agt[2][j], agt[3][j] };
          *(float4*)(XT + (j0 + j)*68 + r0) = t;
        } }
      __syncthreads();
      #pragma unroll 4
      for (int k = 0; k < 64; k++){            // t += agg @ nW1hi
        float4 w = *(const float4*)(Wl + k*64 + j0);
        float4 x = *(const float4*)(XT + k*68 + r0);
        float xv[4] = { x.x, x.y, x.z, x.w };
        float wv[4] = { w.x, w.y, w.z, w.w };
        #pragma unroll
        for (int i = 0; i < 4; i++)
          #pragma unroll
          for (int j = 0; j < 4; j++) acc[i][j] += xv[i]*wv[j];
      }
      #pragma unroll
      for (int i = 0; i < 4; i++)
        #pragma unroll
        for (int j = 0; j < 4; j++) acc[i][j] = silu2(acc[i][j]);
      __syncthreads();
      { const float4* p3 = (const float4*)(nW2 + l*4096);
        float4* d = (float4*)Wl;
        d[tid] = p3[tid]; d[tid+256] = p3[tid+256];
        d[tid+512] = p3[tid+512]; d[tid+768] = p3[tid+768]; }
      #pragma unroll
      for (int j = 0; j < 4; j++){
        float4 t = { acc[0][j], acc[1][j], acc[2][j], acc[3][j] };
        *(float4*)(XT + (j0 + j)*68 + r0) = t;
      }
      float u[4][4];
      { float4 b2 = *(const float4*)(nb2_ + l*64 + j0);
        float bv[4] = { b2.x, b2.y, b2.z, b2.w };
        #pragma unroll
        for (int i = 0; i < 4; i++)
          #pragma unroll
          for (int j = 0; j < 4; j++) u[i][j] = bv[j]; }
      __syncthreads();
      #pragma unroll 4
      for (int k = 0; k < 64; k++){            // u = t @ nW2 + nb2
        float4 w = *(const float4*)(Wl + k*64 + j0);
        float4 x = *(const float4*)(XT + k*68 + r0);
        float xv[4] = { x.x, x.y, x.z, x.w };
        float wv[4] = { w.x, w.y, w.z, w.w };
        #pragma unroll
        for (int i = 0; i < 4; i++)
          #pragma unroll
          for (int j = 0; j < 4; j++) u[i][j] += xv[i]*wv[j];
      }
      float4 lgv = *(const float4*)(lng_ + l*64 + j0);
      float4 lbv = *(const float4*)(lnb_ + l*64 + j0);
      float hn[4][4];
      #pragma unroll
      for (int i = 0; i < 4; i++){
        float hv[4];
        #pragma unroll
        for (int j = 0; j < 4; j++) hv[j] = hold[i][j] + u[i][j];
        float s1 = hv[0]+hv[1]+hv[2]+hv[3];
        float s2 = hv[0]*hv[0]+hv[1]*hv[1]+hv[2]*hv[2]+hv[3]*hv[3];
        s1 += __shfl_xor(s1, 1, 64); s1 += __shfl_xor(s1, 2, 64);
        s1 += __shfl_xor(s1, 4, 64); s1 += __shfl_xor(s1, 8, 64);
        s2 += __shfl_xor(s2, 1, 64); s2 += __shfl_xor(s2, 2, 64);
        s2 += __shfl_xor(s2, 4, 64); s2 += __shfl_xor(s2, 8, 64);
        float mu  = s1 * (1.0f/64.0f);
        float var = s2 * (1.0f/64.0f) - mu*mu;
        float rs  = rsqrtf(var + 1e-5f);
        hn[i][0] = (hv[0]-mu)*rs*lgv.x + lbv.x;
        hn[i][1] = (hv[1]-mu)*rs*lgv.y + lbv.y;
        hn[i][2] = (hv[2]-mu)*rs*lgv.z + lbv.z;
        hn[i][3] = (hv[3]-mu)*rs*lgv.w + lbv.w;
      }

      if (!last){
        #pragma unroll
        for (int i = 0; i < 4; i++){
          float4 v = { hn[i][0], hn[i][1], hn[i][2], hn[i][3] };
          *(float4*)(h + (rowbase + i)*64 + j0) = v;
        }
        __syncthreads();
        { const float4* e1a = (const float4*)(eW1 + (l+1)*8256);
          float4* d = (float4*)Wl;
          d[tid] = e1a[tid]; d[tid+256] = e1a[tid+256];
          d[tid+512] = e1a[tid+512]; d[tid+768] = e1a[tid+768]; }
        #pragma unroll
        for (int j = 0; j < 4; j++){
          float4 t = { hn[0][j], hn[1][j], hn[2][j], hn[3][j] };
          *(float4*)(XT + (j0 + j)*68 + r0) = t;
        }
        float a1r[4][4];
        { float4 b1 = *(const float4*)(eb1_ + (l+1)*64 + j0);
          float bv[4] = { b1.x, b1.y, b1.z, b1.w };
          #pragma unroll
          for (int i = 0; i < 4; i++)
            #pragma unroll
            for (int j = 0; j < 4; j++) a1r[i][j] = bv[j]; }
        __syncthreads();
        #pragma unroll 4
        for (int k = 0; k < 64; k++){          // A1 = hn @ eW1lo + eb1
          float4 w = *(const float4*)(Wl + k*64 + j0);
          float4 x = *(const float4*)(XT + k*68 + r0);
          float xv[4] = { x.x, x.y, x.z, x.w };
          float wv[4] = { w.x, w.y, w.z, w.w };
          #pragma unroll
          for (int i = 0; i < 4; i++)
            #pragma unroll
            for (int j = 0; j < 4; j++) a1r[i][j] += xv[i]*wv[j];
        }
        __syncthreads();
        { const float4* e1b = (const float4*)(eW1 + (l+1)*8256 + 4096);
          float4* d = (float4*)Wl;
          d[tid] = e1b[tid]; d[tid+256] = e1b[tid+256];
          d[tid+512] = e1b[tid+512]; d[tid+768] = e1b[tid+768]; }
        float a2r[4][4];
        #pragma unroll
        for (int i = 0; i < 4; i++)
          #pragma unroll
          for (int j = 0; j < 4; j++) a2r[i][j] = 0.f;
        __syncthreads();
        #pragma unroll 4
        for (int k = 0; k < 64; k++){          // A2 = hn @ eW1hi
          float4 w = *(const float4*)(Wl + k*64 + j0);
          float4 x = *(const float4*)(XT + k*68 + r0);
          float xv[4] = { x.x, x.y, x.z, x.w };
          float wv[4] = { w.x, w.y, w.z, w.w };
          #pragma unroll
          for (int i = 0; i < 4; i++)
            #pragma unroll
            for (int j = 0; j < 4; j++) a2r[i][j] += xv[i]*wv[j];
        }
        #pragma unroll
        for (int i = 0; i < 4; i++){
          int tb = ((n0 + r0 + i)*16 + bb)*64 + j0;
          float4 o1 = { a1r[i][0], a1r[i][1], a1r[i][2], a1r[i][3] };
          *(float4*)(A1t + tb) = o1;
          uint2 pk; pk.x = packbf(a2r[i][0], a2r[i][1]);
          pk.y = packbf(a2r[i][2], a2r[i][3]);
          *(uint2*)(A2bf + tb) = pk;
        }
      } else {
        __syncthreads();
        { const float4* w1p = (const float4*)oW1;
          float4* d = (float4*)Wl;
          d[tid] = w1p[tid]; d[tid+256] = w1p[tid+256];
          d[tid+512] = w1p[tid+512]; d[tid+768] = w1p[tid+768]; }
        if (tid < 192) W2o[tid] = oW2[tid];
        if (tid < 64)  b1s[tid] = ob1_[tid];
        if (tid < 3)   ob2s[tid] = ob2_[tid];
        #pragma unroll
        for (int j = 0; j < 4; j++){
          float4 t = { hn[0][j], hn[1][j], hn[2][j], hn[3][j] };
          *(float4*)(XT + (j0 + j)*68 + r0) = t;
        }
        __syncthreads();
        float tr[4][4];
        { float4 b1 = *(const float4*)(ob1_ + j0);
          float bv[4] = { b1.x, b1.y, b1.z, b1.w };
          #pragma unroll
          for (int i = 0; i < 4; i++)
            #pragma unroll
            for (int j = 0; j < 4; j++) tr[i][j] = bv[j]; }
        #pragma unroll 4
        for (int k = 0; k < 64; k++){          // t = hn @ oW1 + ob1
          float4 w = *(const float4*)(Wl + k*64 + j0);
          float4 x = *(const float4*)(XT + k*68 + r0);
          float xv[4] = { x.x, x.y, x.z, x.w };
          float wv[4] = { w.x, w.y, w.z, w.w };
          #pragma unroll
          for (int i = 0; i < 4; i++)
            #pragma unroll
            for (int j = 0; j < 4; j++) tr[i][j] += xv[i]*wv[j];
        }
        #pragma unroll
        for (int i = 0; i < 4; i++)
          #pragma unroll
          for (int j = 0; j < 4; j++) tr[i][j] = fmaxf(tr[i][j], 0.f);
        float po[4][3];
        #pragma unroll
        for (int i = 0; i < 4; i++){ po[i][0]=0.f; po[i][1]=0.f; po[i][2]=0.f; }
        #pragma unroll
        for (int j = 0; j < 4; j++){
          float w0 = W2o[(j0+j)*3 + 0];
          float w1 = W2o[(j0+j)*3 + 1];
          float w2 = W2o[(j0+j)*3 + 2];
          #pragma unroll
          for (int i = 0; i < 4; i++){
            po[i][0] += tr[i][j]*w0;
            po[i][1] += tr[i][j]*w1;
            po[i][2] += tr[i][j]*w2;
          }
        }
        #pragma unroll
        for (int i = 0; i < 4; i++)
          #pragma unroll
          for (int uu = 0; uu < 3; uu++){
            float v = po[i][uu];
            v += __shfl_xor(v, 1, 64); v += __shfl_xor(v, 2, 64);
            v += __shfl_xor(v, 4, 64); v += __shfl_xor(v, 8, 64);
            po[i][uu] = v;
          }
        if (c == 0){
          #pragma unroll
          for (int i = 0; i < 4; i++){
            int n = n0 + r0 + i;
            out[bb*3072 + n*3 + 0] = po[i][0] + ob2s[0];
            out[bb*3072 + n*3 + 1] = po[i][1] + ob2s[1];
            out[bb*3072 + n*3 + 2] = po[i][2] + ob2s[2];
          }
        }
      }
    }
    if (l < 3) gridbar(bar, gen);
  }
}

} // namespace

extern "C" void kernel_launch(void* const* d_in, const int* in_sizes, int n_in,
                              void* d_out, int out_size, void* d_ws, size_t ws_size,
                              hipStream_t stream){
  const float* z   = (const float*)d_in[0];
  const int*   ei  = (const int*)d_in[1];
  const float* nf  = (const float*)d_in[2];
  const float* Wg  = (const float*)d_in[3];  const float* bg  = (const float*)d_in[4];
  const float* Wn  = (const float*)d_in[5];  const float* bn  = (const float*)d_in[6];
  const float* eW1 = (const float*)d_in[7];  const float* eb1 = (const float*)d_in[8];
  const float* eW2 = (const float*)d_in[9];  const float* eb2 = (const float*)d_in[10];
  const float* nW1 = (const float*)d_in[14]; const float* nb1 = (const float*)d_in[15];
  const float* nW2 = (const float*)d_in[16]; const float* nb2 = (const float*)d_in[17];
  const float* lng = (const float*)d_in[18]; const float* lnb = (const float*)d_in[19];
  const float* oW1 = (const float*)d_in[20]; const float* ob1 = (const float*)d_in[21];
  const float* oW2 = (const float*)d_in[22]; const float* ob2 = (const float*)d_in[23];

  float* W      = (float*)d_ws;
  float* h      = W;                                   // 1,048,576 f
  float* A1t    = W + 1048576;                         // 1,048,576 f
  unsigned short* A2bf   = (unsigned short*)(W + 2097152); // 1,048,576 bf16
  unsigned short* wfragE = (unsigned short*)(W + 2621440); // 16,384 bf16
  float* P      = W + 2629632;                         // 3200*1024 f
  float* g      = W + 5906432;                         // 1024 f
  float* An1    = W + 5907456;                         // 65,536 f
  float* An2    = W + 5972992;                         // 65,536 f
  float* Ag1    = W + 6038528;                         // 1,024 f
  float* Ag2    = W + 6039552;                         // 1,024 f
  int*   cntI   = (int*)(W + 6040576);                 // 1024
  int*   fill   = cntI + 1024;                         // 1024
  int*   ctrl   = fill + 1024;                         // 64: bar, gen, wsteal[4]
  int*   off    = ctrl + 64;                           // 1025
  int*   ioff   = off + 1025;                          // 1025
  int*   items  = ioff + 1025;                         // 3200
  int*   nitems = items + 3200;                        // 1
  int*   ecol   = nitems + 1;                          // 32768

  // zero cntI + fill + ctrl (incl. barrier state and work-steal counters)
  hipMemsetAsync(cntI, 0, (1024 + 1024 + 64)*sizeof(int), stream);
  k_all<<<NBLK, 256, 0, stream>>>(z, ei, nf, Wg, bg, Wn, bn, eW1, eb1, eW2, eb2,
        nW1, nb1, nW2, nb2, lng, lnb, oW1, ob1, oW2, ob2,
        h, A1t, A2bf, wfragE, P, g, An1, An2, Ag1, Ag2,
        cntI, fill, ctrl, off, ioff, items, nitems, ecol, (float*)d_out);
}

// Round 4
// 895.692 us; speedup vs baseline: 1.8998x; 1.8998x over previous
//
#include <hip/hip_runtime.h>
#include <hip/hip_bf16.h>

// Decoder (EGNN) on MI355X. pos==0 identity => stage-2/pos/counts dead.
// ROUND 3: persistent kernel, fence-free barrier, HANG-PROOF poll.
//  - Poll uses atomic fetch_add(gen,0) (RMW always served at MALL coherence
//    point -> cannot read stale, unlike a relaxed atomic load which may be
//    cache-serviced). Round-2's relaxed-load spin is the suspected hang.
//  - All cross-block inter-phase data uses agent-scope RELAXED atomics
//    (coherent at MALL; no buffer_wbl2/buffer_inv anywhere -- round-1's
//    fenced barrier cost ~150us/barrier).
//  - Edge gathers now come from MALL: ecol for the whole chunk preloaded
//    once + __shfl-distributed; A2bf prefetched 2-deep (named bufs, static
//    indexing) to cover ~700-900cy MALL latency.
// Phases: ph0 An|g+Ag|wfrag|count ; ph1 scan ; ph2 bucket + hold/A init ;
//         4x { edge (wave work-steal, MFMA) | post (4x4 reg tiles) }.

namespace {

constexpr int kE = 32768, kLat = 128;
constexpr int kC = 16;                 // edges per wave-chunk
constexpr int NBLK = 512;              // 2 blocks/CU co-resident (LDS 38KB)

typedef unsigned long long u64;
typedef __attribute__((ext_vector_type(8))) short short8;   // 8 bf16
typedef __attribute__((ext_vector_type(4))) float floatx4;

__device__ __forceinline__ unsigned short f2bf(float f){   // RNE
  union { float f; unsigned int u; } v; v.f = f;
  unsigned int r = v.u + 0x7fffu + ((v.u >> 16) & 1u);
  return (unsigned short)(r >> 16);
}
__device__ __forceinline__ unsigned int packbf(float a, float b){
  return ((unsigned int)f2bf(b) << 16) | (unsigned int)f2bf(a);
}
__device__ __forceinline__ unsigned int pack2f(float a, float b){ // fast half-up
  unsigned int ua = __float_as_uint(a) + 0x8000u;
  unsigned int ub = __float_as_uint(b) + 0x8000u;
  return __builtin_amdgcn_perm(ub, ua, 0x07060302);
}
__device__ __forceinline__ float bflo(unsigned int u){
  union { unsigned int u; float f; } v; v.u = u << 16; return v.f;
}
__device__ __forceinline__ float bfhi(unsigned int u){
  union { unsigned int u; float f; } v; v.u = u & 0xffff0000u; return v.f;
}
__device__ __forceinline__ float silu2(float x){   // 2 trans + 3 alu
  float u = __builtin_amdgcn_exp2f(-1.44269504f * x);
  return x * __builtin_amdgcn_rcpf(1.0f + u);
}

// ---- agent-scope coherent accessors (no cache maintenance needed) ----------
__device__ __forceinline__ u64 ald(const void* p){
  return __hip_atomic_load((u64*)p, __ATOMIC_RELAXED, __HIP_MEMORY_SCOPE_AGENT);
}
__device__ __forceinline__ void ast(void* p, u64 v){
  __hip_atomic_store((u64*)p, v, __ATOMIC_RELAXED, __HIP_MEMORY_SCOPE_AGENT);
}
__device__ __forceinline__ int ald4(const int* p){
  return __hip_atomic_load((int*)p, __ATOMIC_RELAXED, __HIP_MEMORY_SCOPE_AGENT);
}
__device__ __forceinline__ void ast4(int* p, int v){
  __hip_atomic_store(p, v, __ATOMIC_RELAXED, __HIP_MEMORY_SCOPE_AGENT);
}
__device__ __forceinline__ int armw(int* p){   // coherence-point read (RMW +0)
  return __hip_atomic_fetch_add(p, 0, __ATOMIC_RELAXED, __HIP_MEMORY_SCOPE_AGENT);
}
union UF2 { u64 u; float f[2]; unsigned int w[2]; };
__device__ __forceinline__ float4 aldf4(const float* p){
  UF2 a, b; a.u = ald(p); b.u = ald(p + 2);
  float4 r; r.x = a.f[0]; r.y = a.f[1]; r.z = b.f[0]; r.w = b.f[1];
  return r;
}
__device__ __forceinline__ void astf4(float* p, float4 v){
  UF2 a, b; a.f[0] = v.x; a.f[1] = v.y; b.f[0] = v.z; b.f[1] = v.w;
  ast(p, a.u); ast(p + 2, b.u);
}

// Fence-free grid barrier, RMW-polled (hang-proof: RMW is always served at
// the MALL coherence point). Data moved between phases is itself
// agent-coherent, so vmcnt drain == global visibility.
__device__ __forceinline__ void gridbar(int* bar, int* gen){
  __syncthreads();
  if (threadIdx.x == 0){
    asm volatile("s_waitcnt vmcnt(0) lgkmcnt(0)" ::: "memory");
    int g = armw(gen);
    int a = __hip_atomic_fetch_add(bar, 1, __ATOMIC_RELAXED, __HIP_MEMORY_SCOPE_AGENT);
    if (a == NBLK - 1){
      __hip_atomic_store(bar, 0, __ATOMIC_RELAXED, __HIP_MEMORY_SCOPE_AGENT);
      asm volatile("s_waitcnt vmcnt(0)" ::: "memory");   // reset lands first
      __hip_atomic_fetch_add(gen, 1, __ATOMIC_RELAXED, __HIP_MEMORY_SCOPE_AGENT);
    } else {
      while (armw(gen) == g)
        __builtin_amdgcn_s_sleep(16);
    }
  }
  __syncthreads();
}

__global__ __launch_bounds__(256, 2) void k_all(
    const float* z, const int* ei, const float* nf,
    const float* Wg, const float* bg, const float* Wn, const float* bn,
    const float* eW1, const float* eb1_, const float* eW2, const float* eb2,
    const float* nW1, const float* nb1_, const float* nW2, const float* nb2_,
    const float* lng_, const float* lnb_,
    const float* oW1, const float* ob1_, const float* oW2, const float* ob2_,
    float* A1t, unsigned short* A2bf, unsigned short* wfragE,
    float* P, float* g, float* An1, float* An2, float* Ag1, float* Ag2,
    int* cntI, int* fill, int* ctrl, int* off, int* ioff, int* items,
    int* nitems, int* ecol, float* out){
  __shared__ __align__(16) float SM[9280];  // union: ph0 W0|W1|HR ; scan ; post W|XT
  __shared__ float W2o[192];
  __shared__ float ob2s[4];
  int tid = threadIdx.x, bid = blockIdx.x;
  int* bar = ctrl; int* gen = ctrl + 1; int* wsteal = ctrl + 2;

  // ================= ph0 =================
  if (bid < 64){                      // An1/An2 = (nf@Wn+bn) @ eW1[0]
    float* W0 = SM; float* W1 = SM + 4096; float* HR = SM + 8192;
    const float4* e1a = (const float4*)(eW1);
    const float4* e1b = (const float4*)(eW1 + 4096);
    for (int i = tid; i < 1024; i += 256){
      ((float4*)W0)[i] = e1a[i]; ((float4*)W1)[i] = e1b[i];
    }
    int rl = tid >> 4, c = tid & 15, j0 = c*4;
    int n = bid*16 + rl;
    float f0 = nf[n*3], f1 = nf[n*3+1], f2 = nf[n*3+2];
    float4 hv;
    hv.x = f0*Wn[j0+0] + f1*Wn[64+j0+0] + f2*Wn[128+j0+0] + bn[j0+0];
    hv.y = f0*Wn[j0+1] + f1*Wn[64+j0+1] + f2*Wn[128+j0+1] + bn[j0+1];
    hv.z = f0*Wn[j0+2] + f1*Wn[64+j0+2] + f2*Wn[128+j0+2] + bn[j0+2];
    hv.w = f0*Wn[j0+3] + f1*Wn[64+j0+3] + f2*Wn[128+j0+3] + bn[j0+3];
    *(float4*)(HR + rl*68 + j0) = hv;
    __syncthreads();
    float4 b1 = *(const float4*)(eb1_ + j0);
    float a1[4] = { b1.x, b1.y, b1.z, b1.w };
    float a2[4] = { 0.f, 0.f, 0.f, 0.f };
    #pragma unroll 8
    for (int k = 0; k < 64; k++){
      float hk = HR[rl*68 + k];
      float4 w1 = *(const float4*)(W0 + k*64 + j0);
      float4 w2 = *(const float4*)(W1 + k*64 + j0);
      a1[0] += hk*w1.x; a1[1] += hk*w1.y; a1[2] += hk*w1.z; a1[3] += hk*w1.w;
      a2[0] += hk*w2.x; a2[1] += hk*w2.y; a2[2] += hk*w2.z; a2[3] += hk*w2.w;
    }
    float4 o1; o1.x=a1[0]; o1.y=a1[1]; o1.z=a1[2]; o1.w=a1[3];
    float4 o2; o2.x=a2[0]; o2.y=a2[1]; o2.z=a2[2]; o2.w=a2[3];
    astf4(An1 + n*64 + j0, o1);
    astf4(An2 + n*64 + j0, o2);
  } else if (bid == 64){              // g = z@Wg+bg ; Ag = g @ eW1[0] (g in LDS)
    float* GS = SM;
    int bb = tid >> 4, j0 = (tid & 15)*4;
    float4 acc = *(const float4*)(bg + j0);
    for (int k = 0; k < kLat; k++){
      float zk = z[bb*kLat + k];
      float4 w = *(const float4*)(Wg + k*64 + j0);
      acc.x += zk*w.x; acc.y += zk*w.y; acc.z += zk*w.z; acc.w += zk*w.w;
    }
    astf4(g + bb*64 + j0, acc);
    *(float4*)(GS + bb*64 + j0) = acc;
    __syncthreads();
    float a1[4] = {0.f,0.f,0.f,0.f}, a2[4] = {0.f,0.f,0.f,0.f};
    for (int k = 0; k < 64; k++){
      float gk = GS[bb*64 + k];
      float4 w1 = *(const float4*)(eW1 + k*64 + j0);
      float4 w2 = *(const float4*)(eW1 + 4096 + k*64 + j0);
      a1[0] += gk*w1.x; a1[1] += gk*w1.y; a1[2] += gk*w1.z; a1[3] += gk*w1.w;
      a2[0] += gk*w2.x; a2[1] += gk*w2.y; a2[2] += gk*w2.z; a2[3] += gk*w2.w;
    }
    float4 o1; o1.x=a1[0]; o1.y=a1[1]; o1.z=a1[2]; o1.w=a1[3];
    float4 o2; o2.x=a2[0]; o2.y=a2[1]; o2.z=a2[2]; o2.w=a2[3];
    astf4(Ag1 + bb*64 + j0, o1);
    astf4(Ag2 + bb*64 + j0, o2);
  } else if (bid >= 66 && bid < 70){  // wfrag (MFMA A-fragments of eW2)
    int l = bid - 66;
    for (int q = tid; q < 1024; q += 256){
      int i0 = q*4;
      int f = i0 >> 9, lane = (i0 >> 3) & 63, j8 = i0 & 7;
      int jt = f >> 1, ks = f & 1;
      int kb = ks*32 + (lane >> 4)*8 + j8;
      int j = jt*16 + (lane & 15);
      const float* src = eW2 + l*4096 + kb*64 + j;
      u64 v = (u64)f2bf(src[0])
            | ((u64)f2bf(src[64])  << 16)
            | ((u64)f2bf(src[128]) << 32)
            | ((u64)f2bf(src[192]) << 48);
      ast(wfragE + l*4096 + i0, v);
    }
  } else if (bid >= 72 && bid < 200){ // count (cntI zeroed by memset)
    int e = (bid - 72)*256 + tid;
    atomicAdd(&cntI[ei[e]], 1);
  }
  gridbar(bar, gen);

  // ================= ph1: scan (bid 0 only) =================
  if (bid == 0){
    int* s0 = (int*)SM; int* s1 = s0 + 1024;
    for (int i = tid; i < 1024; i += 256) s0[i] = ald4(cntI + i);
    __syncthreads();
    int* src = s0; int* dst = s1;
    for (int o = 1; o < 1024; o <<= 1){
      for (int i = tid; i < 1024; i += 256)
        dst[i] = src[i] + ((i >= o) ? src[i-o] : 0);
      __syncthreads();
      int* t_ = src; src = dst; dst = t_;
    }
    for (int i = tid; i < 1024; i += 256) ast4(off + i, src[i] - ald4(cntI + i));
    if (tid == 0) ast4(off + 1024, src[1023]);
    __syncthreads();
    for (int i = tid; i < 1024; i += 256) dst[i] = (ald4(cntI + i) + (kC-1))/kC;
    __syncthreads();
    int* src2 = dst; int* dst2 = src;
    for (int o = 1; o < 1024; o <<= 1){
      for (int i = tid; i < 1024; i += 256)
        dst2[i] = src2[i] + ((i >= o) ? src2[i-o] : 0);
      __syncthreads();
      int* t_ = src2; src2 = dst2; dst2 = t_;
    }
    for (int i = tid; i < 1024; i += 256){
      int ic = (ald4(cntI + i) + (kC-1))/kC;
      int ib = src2[i] - ic;
      ast4(ioff + i, ib);
      for (int s = 0; s < ic; s++) ast4(items + ib + s, (i << 12) | s);
    }
    if (tid == 0){ ast4(ioff + 1024, src2[1023]); ast4(nitems, src2[1023]); }
  }
  gridbar(bar, gen);

  // ================= ph2: bucket + local hold/A init =================
  if (tid < 64){
    int e = bid*64 + tid;
    int r = ei[e];
    int s = atomicAdd(&fill[r], 1);
    ast4(ecol + ald4(off + r) + s, ei[kE + e]);
  }
  float hold[4][4];                    // post-block register-resident h tile
  if (bid < 256){
    int bb = bid >> 4, n0 = (bid & 15) * 64;
    int c = tid & 15, gq = tid >> 4;
    int j0 = c*4, r0 = gq*4;
    float4 gv  = aldf4(g + bb*64 + j0);
    float4 ag1 = aldf4(Ag1 + bb*64 + j0);
    float4 ag2 = aldf4(Ag2 + bb*64 + j0);
    float4 w0 = *(const float4*)(Wn + j0);
    float4 w1 = *(const float4*)(Wn + 64 + j0);
    float4 w2 = *(const float4*)(Wn + 128 + j0);
    float4 bv = *(const float4*)(bn + j0);
    #pragma unroll
    for (int i = 0; i < 4; i++){
      int n = n0 + r0 + i;
      float f0 = nf[n*3], f1 = nf[n*3+1], f2 = nf[n*3+2];
      hold[i][0] = f0*w0.x + f1*w1.x + f2*w2.x + bv.x + gv.x;
      hold[i][1] = f0*w0.y + f1*w1.y + f2*w2.y + bv.y + gv.y;
      hold[i][2] = f0*w0.z + f1*w1.z + f2*w2.z + bv.z + gv.z;
      hold[i][3] = f0*w0.w + f1*w1.w + f2*w2.w + bv.w + gv.w;
      float4 a1 = aldf4(An1 + n*64 + j0);
      a1.x += ag1.x; a1.y += ag1.y; a1.z += ag1.z; a1.w += ag1.w;
      astf4(A1t + (n*16 + bb)*64 + j0, a1);
      float4 a2 = aldf4(An2 + n*64 + j0);
      a2.x += ag2.x; a2.y += ag2.y; a2.z += ag2.z; a2.w += ag2.w;
      u64 pk = (u64)packbf(a2.x, a2.y) | ((u64)packbf(a2.z, a2.w) << 32);
      ast(A2bf + (n*16 + bb)*64 + j0, pk);
    }
  }
  gridbar(bar, gen);

  int nit = ald4(nitems);
  int lane = tid & 63, m = lane & 15, quad = lane >> 4;

  for (int l = 0; l < 4; l++){
    // ---------------- edge: wave work-steal over chunks ----------------
    short8 wf[8];
    #pragma unroll
    for (int f = 0; f < 8; f++){
      const unsigned short* wp = wfragE + l*4096 + f*512 + lane*8;
      union { u64 u[2]; short8 s; } t;
      t.u[0] = ald(wp); t.u[1] = ald(wp + 4);
      wf[f] = t.s;
    }
    for (;;){
      int w = 0;
      if (lane == 0) w = atomicAdd(&wsteal[l], 1);
      w = __shfl(w, 0, 64);
      if (w >= nit) break;
      int it = ald4(items + w);
      int r = it >> 12, s = it & 4095;
      int e0 = ald4(off + r) + s*kC;
      int e1 = min(ald4(off + r + 1), e0 + kC);
      int ne = e1 - e0;                               // 1..16
      int ecl = ald4(ecol + e0 + min(lane & 15, ne - 1));  // chunk cols, 1/lane
      float4 a1[4];
      #pragma unroll
      for (int ks = 0; ks < 2; ks++){
        a1[ks*2+0] = aldf4(A1t + (r<<10) + (m<<6) + ks*32 + quad*8);
        a1[ks*2+1] = aldf4(A1t + (r<<10) + (m<<6) + ks*32 + quad*8 + 4);
      }
      floatx4 dini[4], agg[4];
      #pragma unroll
      for (int jt = 0; jt < 4; jt++){
        dini[jt] = *(const floatx4*)(eb2 + l*64 + jt*16 + quad*4);
        agg[jt] = (floatx4){0.f,0.f,0.f,0.f};
      }
      auto consume = [&](u64 c00, u64 c01, u64 c10, u64 c11){
        short8 bfr[2];
        #pragma unroll
        for (int ks = 0; ks < 2; ks++){
          UF2 ua, ub; ua.u = (ks == 0) ? c00 : c10; ub.u = (ks == 0) ? c01 : c11;
          float4 x0 = a1[ks*2+0];
          float4 x1 = a1[ks*2+1];
          float v0 = silu2(x0.x + bflo(ua.w[0]));
          float v1 = silu2(x0.y + bfhi(ua.w[0]));
          float v2 = silu2(x0.z + bflo(ua.w[1]));
          float v3 = silu2(x0.w + bfhi(ua.w[1]));
          float v4 = silu2(x1.x + bflo(ub.w[0]));
          float v5 = silu2(x1.y + bfhi(ub.w[0]));
          float v6 = silu2(x1.z + bflo(ub.w[1]));
          float v7 = silu2(x1.w + bfhi(ub.w[1]));
          union { uint4 u; short8 s; } bu;
          bu.u.x = pack2f(v0, v1); bu.u.y = pack2f(v2, v3);
          bu.u.z = pack2f(v4, v5); bu.u.w = pack2f(v6, v7);
          bfr[ks] = bu.s;
        }
        #pragma unroll
        for (int jt = 0; jt < 4; jt++){
          floatx4 d = dini[jt];
          d = __builtin_amdgcn_mfma_f32_16x16x32_bf16(wf[jt*2+0], bfr[0], d, 0, 0, 0);
          d = __builtin_amdgcn_mfma_f32_16x16x32_bf16(wf[jt*2+1], bfr[1], d, 0, 0, 0);
          floatx4 a = agg[jt];
          a.x += silu2(d.x); a.y += silu2(d.y);
          a.z += silu2(d.z); a.w += silu2(d.w);
          agg[jt] = a;
        }
      };
      // 2-deep prefetch, statically-named buffers (A = even slots, B = odd)
      int cA = __shfl(ecl, 0, 16);
      const unsigned short* qA = A2bf + ((cA<<4) + m)*64 + quad*8;
      u64 a00 = ald(qA), a01 = ald(qA + 4), a10 = ald(qA + 32), a11 = ald(qA + 36);
      u64 b00 = 0, b01 = 0, b10 = 0, b11 = 0;
      if (ne > 1){
        int cB = __shfl(ecl, 1, 16);
        const unsigned short* qB = A2bf + ((cB<<4) + m)*64 + quad*8;
        b00 = ald(qB); b01 = ald(qB + 4); b10 = ald(qB + 32); b11 = ald(qB + 36);
      }
      for (int t = 0; t < ne; t += 2){
        u64 n00 = a00, n01 = a01, n10 = a10, n11 = a11;
        if (t + 2 < ne){
          int cn = __shfl(ecl, t + 2, 16);
          const unsigned short* qn = A2bf + ((cn<<4) + m)*64 + quad*8;
          a00 = ald(qn); a01 = ald(qn + 4); a10 = ald(qn + 32); a11 = ald(qn + 36);
        }
        consume(n00, n01, n10, n11);
        if (t + 1 < ne){
          u64 m00 = b00, m01 = b01, m10 = b10, m11 = b11;
          if (t + 3 < ne){
            int cn = __shfl(ecl, t + 3, 16);
            const unsigned short* qn = A2bf + ((cn<<4) + m)*64 + quad*8;
            b00 = ald(qn); b01 = ald(qn + 4); b10 = ald(qn + 32); b11 = ald(qn + 36);
          }
          consume(m00, m01, m10, m11);
        }
      }
      #pragma unroll
      for (int jt = 0; jt < 4; jt++){
        float4 o; o.x = agg[jt].x; o.y = agg[jt].y; o.z = agg[jt].z; o.w = agg[jt].w;
        astf4(P + w*1024 + m*64 + jt*16 + quad*4, o);
      }
    }
    gridbar(bar, gen);

    // ---------------- post: bids 0..255 (64 rows, 4x4 reg tiles) -------
    if (bid < 256){
      bool last = (l == 3);
      float* Wl = SM; float* XT = SM + 4096;     // XT stride 68
      int bb = bid >> 4;
      int n0 = (bid & 15) * 64;
      int c = tid & 15, gq = tid >> 4;
      int j0 = c*4, r0 = gq*4;

      { const float4* p1 = (const float4*)(nW1 + l*8192);
        float4* d = (float4*)Wl;
        d[tid] = p1[tid]; d[tid+256] = p1[tid+256];
        d[tid+512] = p1[tid+512]; d[tid+768] = p1[tid+768]; }
      #pragma unroll
      for (int j = 0; j < 4; j++){
        float4 t; t.x = hold[0][j]; t.y = hold[1][j]; t.z = hold[2][j]; t.w = hold[3][j];
        *(float4*)(XT + (j0 + j)*68 + r0) = t;
      }
      float acc[4][4];
      { float4 b1 = *(const float4*)(nb1_ + l*64 + j0);
        float bv[4] = { b1.x, b1.y, b1.z, b1.w };
        #pragma unroll
        for (int i = 0; i < 4; i++)
          #pragma unroll
          for (int j = 0; j < 4; j++) acc[i][j] = bv[j]; }
      __syncthreads();
      #pragma unroll 4
      for (int k = 0; k < 64; k++){            // t += h @ nW1lo
        float4 w = *(const float4*)(Wl + k*64 + j0);
        float4 x = *(const float4*)(XT + k*68 + r0);
        float xv[4] = { x.x, x.y, x.z, x.w };
        float wv[4] = { w.x, w.y, w.z, w.w };
        #pragma unroll
        for (int i = 0; i < 4; i++)
          #pragma unroll
          for (int j = 0; j < 4; j++) acc[i][j] += xv[i]*wv[j];
      }
      __syncthreads();
      { const float4* p2 = (const float4*)(nW1 + l*8192 + 4096);
        float4* d = (float4*)Wl;
        d[tid] = p2[tid]; d[tid+256] = p2[tid+256];
        d[tid+512] = p2[tid+512]; d[tid+768] = p2[tid+768]; }
      { float agt[4][4];
        #pragma unroll
        for (int i = 0; i < 4; i++){
          int n = n0 + r0 + i;
          float4 sv; sv.x = 0.f; sv.y = 0.f; sv.z = 0.f; sv.w = 0.f;
          int i0 = ald4(ioff + n), i1 = ald4(ioff + n + 1);
          for (int it = i0; it < i1; it++){
            float4 v = aldf4(P + it*1024 + bb*64 + j0);
            sv.x += v.x; sv.y += v.y; sv.z += v.z; sv.w += v.w;
          }
          agt[i][0]=sv.x; agt[i][1]=sv.y; agt[i][2]=sv.z; agt[i][3]=sv.w;
        }
        #pragma unroll
        for (int j = 0; j < 4; j++){
          float4 t; t.x = agt[0][j]; t.y = agt[1][j]; t.z = agt[2][j]; t.w = agt[3][j];
          *(float4*)(XT + (j0 + j)*68 + r0) = t;
        } }
      __syncthreads();
      #pragma unroll 4
      for (int k = 0; k < 64; k++){            // t += agg @ nW1hi
        float4 w = *(const float4*)(Wl + k*64 + j0);
        float4 x = *(const float4*)(XT + k*68 + r0);
        float xv[4] = { x.x, x.y, x.z, x.w };
        float wv[4] = { w.x, w.y, w.z, w.w };
        #pragma unroll
        for (int i = 0; i < 4; i++)
          #pragma unroll
          for (int j = 0; j < 4; j++) acc[i][j] += xv[i]*wv[j];
      }
      #pragma unroll
      for (int i = 0; i < 4; i++)
        #pragma unroll
        for (int j = 0; j < 4; j++) acc[i][j] = silu2(acc[i][j]);
      __syncthreads();
      { const float4* p3 = (const float4*)(nW2 + l*4096);
        float4* d = (float4*)Wl;
        d[tid] = p3[tid]; d[tid+256] = p3[tid+256];
        d[tid+512] = p3[tid+512]; d[tid+768] = p3[tid+768]; }
      #pragma unroll
      for (int j = 0; j < 4; j++){
        float4 t; t.x = acc[0][j]; t.y = acc[1][j]; t.z = acc[2][j]; t.w = acc[3][j];
        *(float4*)(XT + (j0 + j)*68 + r0) = t;
      }
      float u[4][4];
      { float4 b2 = *(const float4*)(nb2_ + l*64 + j0);
        float bv[4] = { b2.x, b2.y, b2.z, b2.w };
        #pragma unroll
        for (int i = 0; i < 4; i++)
          #pragma unroll
          for (int j = 0; j < 4; j++) u[i][j] = bv[j]; }
      __syncthreads();
      #pragma unroll 4
      for (int k = 0; k < 64; k++){            // u = t @ nW2 + nb2
        float4 w = *(const float4*)(Wl + k*64 + j0);
        float4 x = *(const float4*)(XT + k*68 + r0);
        float xv[4] = { x.x, x.y, x.z, x.w };
        float wv[4] = { w.x, w.y, w.z, w.w };
        #pragma unroll
        for (int i = 0; i < 4; i++)
          #pragma unroll
          for (int j = 0; j < 4; j++) u[i][j] += xv[i]*wv[j];
      }
      float4 lgv = *(const float4*)(lng_ + l*64 + j0);
      float4 lbv = *(const float4*)(lnb_ + l*64 + j0);
      float hn[4][4];
      #pragma unroll
      for (int i = 0; i < 4; i++){
        float hv[4];
        #pragma unroll
        for (int j = 0; j < 4; j++) hv[j] = hold[i][j] + u[i][j];
        float s1 = hv[0]+hv[1]+hv[2]+hv[3];
        float s2 = hv[0]*hv[0]+hv[1]*hv[1]+hv[2]*hv[2]+hv[3]*hv[3];
        s1 += __shfl_xor(s1, 1, 64); s1 += __shfl_xor(s1, 2, 64);
        s1 += __shfl_xor(s1, 4, 64); s1 += __shfl_xor(s1, 8, 64);
        s2 += __shfl_xor(s2, 1, 64); s2 += __shfl_xor(s2, 2, 64);
        s2 += __shfl_xor(s2, 4, 64); s2 += __shfl_xor(s2, 8, 64);
        float mu  = s1 * (1.0f/64.0f);
        float var = s2 * (1.0f/64.0f) - mu*mu;
        float rs  = rsqrtf(var + 1e-5f);
        hn[i][0] = (hv[0]-mu)*rs*lgv.x + lbv.x;
        hn[i][1] = (hv[1]-mu)*rs*lgv.y + lbv.y;
        hn[i][2] = (hv[2]-mu)*rs*lgv.z + lbv.z;
        hn[i][3] = (hv[3]-mu)*rs*lgv.w + lbv.w;
      }

      if (!last){
        #pragma unroll
        for (int i = 0; i < 4; i++)
          #pragma unroll
          for (int j = 0; j < 4; j++) hold[i][j] = hn[i][j];
        __syncthreads();
        { const float4* e1a = (const float4*)(eW1 + (l+1)*8256);
          float4* d = (float4*)Wl;
          d[tid] = e1a[tid]; d[tid+256] = e1a[tid+256];
          d[tid+512] = e1a[tid+512]; d[tid+768] = e1a[tid+768]; }
        #pragma unroll
        for (int j = 0; j < 4; j++){
          float4 t; t.x = hn[0][j]; t.y = hn[1][j]; t.z = hn[2][j]; t.w = hn[3][j];
          *(float4*)(XT + (j0 + j)*68 + r0) = t;
        }
        float a1r[4][4];
        { float4 b1 = *(const float4*)(eb1_ + (l+1)*64 + j0);
          float bv[4] = { b1.x, b1.y, b1.z, b1.w };
          #pragma unroll
          for (int i = 0; i < 4; i++)
            #pragma unroll
            for (int j = 0; j < 4; j++) a1r[i][j] = bv[j]; }
        __syncthreads();
        #pragma unroll 4
        for (int k = 0; k < 64; k++){          // A1 = hn @ eW1lo + eb1
          float4 w = *(const float4*)(Wl + k*64 + j0);
          float4 x = *(const float4*)(XT + k*68 + r0);
          float xv[4] = { x.x, x.y, x.z, x.w };
          float wv[4] = { w.x, w.y, w.z, w.w };
          #pragma unroll
          for (int i = 0; i < 4; i++)
            #pragma unroll
            for (int j = 0; j < 4; j++) a1r[i][j] += xv[i]*wv[j];
        }
        __syncthreads();
        { const float4* e1b = (const float4*)(eW1 + (l+1)*8256 + 4096);
          float4* d = (float4*)Wl;
          d[tid] = e1b[tid]; d[tid+256] = e1b[tid+256];
          d[tid+512] = e1b[tid+512]; d[tid+768] = e1b[tid+768]; }
        float a2r[4][4];
        #pragma unroll
        for (int i = 0; i < 4; i++)
          #pragma unroll
          for (int j = 0; j < 4; j++) a2r[i][j] = 0.f;
        __syncthreads();
        #pragma unroll 4
        for (int k = 0; k < 64; k++){          // A2 = hn @ eW1hi
          float4 w = *(const float4*)(Wl + k*64 + j0);
          float4 x = *(const float4*)(XT + k*68 + r0);
          float xv[4] = { x.x, x.y, x.z, x.w };
          float wv[4] = { w.x, w.y, w.z, w.w };
          #pragma unroll
          for (int i = 0; i < 4; i++)
            #pragma unroll
            for (int j = 0; j < 4; j++) a2r[i][j] += xv[i]*wv[j];
        }
        #pragma unroll
        for (int i = 0; i < 4; i++){
          int tb = ((n0 + r0 + i)*16 + bb)*64 + j0;
          float4 o1; o1.x=a1r[i][0]; o1.y=a1r[i][1]; o1.z=a1r[i][2]; o1.w=a1r[i][3];
          astf4(A1t + tb, o1);
          u64 pk = (u64)packbf(a2r[i][0], a2r[i][1])
                 | ((u64)packbf(a2r[i][2], a2r[i][3]) << 32);
          ast(A2bf + tb, pk);
        }
      } else {
        __syncthreads();
        { const float4* w1p = (const float4*)oW1;
          float4* d = (float4*)Wl;
          d[tid] = w1p[tid]; d[tid+256] = w1p[tid+256];
          d[tid+512] = w1p[tid+512]; d[tid+768] = w1p[tid+768]; }
        if (tid < 192) W2o[tid] = oW2[tid];
        if (tid < 3)   ob2s[tid] = ob2_[tid];
        #pragma unroll
        for (int j = 0; j < 4; j++){
          float4 t; t.x = hn[0][j]; t.y = hn[1][j]; t.z = hn[2][j]; t.w = hn[3][j];
          *(float4*)(XT + (j0 + j)*68 + r0) = t;
        }
        __syncthreads();
        float tr[4][4];
        { float4 b1 = *(const float4*)(ob1_ + j0);
          float bv[4] = { b1.x, b1.y, b1.z, b1.w };
          #pragma unroll
          for (int i = 0; i < 4; i++)
            #pragma unroll
            for (int j = 0; j < 4; j++) tr[i][j] = bv[j]; }
        #pragma unroll 4
        for (int k = 0; k < 64; k++){          // t = hn @ oW1 + ob1
          float4 w = *(const float4*)(Wl + k*64 + j0);
          float4 x = *(const float4*)(XT + k*68 + r0);
          float xv[4] = { x.x, x.y, x.z, x.w };
          float wv[4] = { w.x, w.y, w.z, w.w };
          #pragma unroll
          for (int i = 0; i < 4; i++)
            #pragma unroll
            for (int j = 0; j < 4; j++) tr[i][j] += xv[i]*wv[j];
        }
        #pragma unroll
        for (int i = 0; i < 4; i++)
          #pragma unroll
          for (int j = 0; j < 4; j++) tr[i][j] = fmaxf(tr[i][j], 0.f);
        float po[4][3];
        #pragma unroll
        for (int i = 0; i < 4; i++){ po[i][0]=0.f; po[i][1]=0.f; po[i][2]=0.f; }
        #pragma unroll
        for (int j = 0; j < 4; j++){
          float w0 = W2o[(j0+j)*3 + 0];
          float w1 = W2o[(j0+j)*3 + 1];
          float w2 = W2o[(j0+j)*3 + 2];
          #pragma unroll
          for (int i = 0; i < 4; i++){
            po[i][0] += tr[i][j]*w0;
            po[i][1] += tr[i][j]*w1;
            po[i][2] += tr[i][j]*w2;
          }
        }
        #pragma unroll
        for (int i = 0; i < 4; i++)
          #pragma unroll
          for (int uu = 0; uu < 3; uu++){
            float v = po[i][uu];
            v += __shfl_xor(v, 1, 64); v += __shfl_xor(v, 2, 64);
            v += __shfl_xor(v, 4, 64); v += __shfl_xor(v, 8, 64);
            po[i][uu] = v;
          }
        if (c == 0){
          #pragma unroll
          for (int i = 0; i < 4; i++){
            int n = n0 + r0 + i;
            out[bb*3072 + n*3 + 0] = po[i][0] + ob2s[0];
            out[bb*3072 + n*3 + 1] = po[i][1] + ob2s[1];
            out[bb*3072 + n*3 + 2] = po[i][2] + ob2s[2];
          }
        }
      }
    }
    if (l < 3) gridbar(bar, gen);
  }
}

} // namespace

extern "C" void kernel_launch(void* const* d_in, const int* in_sizes, int n_in,
                              void* d_out, int out_size, void* d_ws, size_t ws_size,
                              hipStream_t stream){
  const float* z   = (const float*)d_in[0];
  const int*   ei  = (const int*)d_in[1];
  const float* nf  = (const float*)d_in[2];
  const float* Wg  = (const float*)d_in[3];  const float* bg  = (const float*)d_in[4];
  const float* Wn  = (const float*)d_in[5];  const float* bn  = (const float*)d_in[6];
  const float* eW1 = (const float*)d_in[7];  const float* eb1 = (const float*)d_in[8];
  const float* eW2 = (const float*)d_in[9];  const float* eb2 = (const float*)d_in[10];
  const float* nW1 = (const float*)d_in[14]; const float* nb1 = (const float*)d_in[15];
  const float* nW2 = (const float*)d_in[16]; const float* nb2 = (const float*)d_in[17];
  const float* lng = (const float*)d_in[18]; const float* lnb = (const float*)d_in[19];
  const float* oW1 = (const float*)d_in[20]; const float* ob1 = (const float*)d_in[21];
  const float* oW2 = (const float*)d_in[22]; const float* ob2 = (const float*)d_in[23];

  float* W      = (float*)d_ws;
  float* A1t    = W + 1048576;                         // 1,048,576 f
  unsigned short* A2bf   = (unsigned short*)(W + 2097152); // 1,048,576 bf16
  unsigned short* wfragE = (unsigned short*)(W + 2621440); // 16,384 bf16
  float* P      = W + 2629632;                         // 3200*1024 f
  float* g      = W + 5906432;                         // 1024 f
  float* An1    = W + 5907456;                         // 65,536 f
  float* An2    = W + 5972992;                         // 65,536 f
  float* Ag1    = W + 6038528;                         // 1,024 f
  float* Ag2    = W + 6039552;                         // 1,024 f
  int*   cntI   = (int*)(W + 6040576);                 // 1024
  int*   fill   = cntI + 1024;                         // 1024
  int*   ctrl   = fill + 1024;                         // 64: bar, gen, wsteal[4]
  int*   off    = ctrl + 64;                           // 1025
  int*   ioff   = off + 1025;                          // 1025
  int*   items  = ioff + 1025;                         // 3200
  int*   nitems = items + 3200;                        // 1
  int*   ecol   = nitems + 1;                          // 32768

  // zero cntI + fill + ctrl (barrier state, gen, work-steal counters)
  hipMemsetAsync(cntI, 0, (1024 + 1024 + 64)*sizeof(int), stream);
  k_all<<<NBLK, 256, 0, stream>>>(z, ei, nf, Wg, bg, Wn, bn, eW1, eb1, eW2, eb2,
        nW1, nb1, nW2, nb2, lng, lnb, oW1, ob1, oW2, ob2,
        A1t, A2bf, wfragE, P, g, An1, An2, Ag1, Ag2,
        cntI, fill, ctrl, off, ioff, items, nitems, ecol, (float*)d_out);
}

// Round 5
// 336.242 us; speedup vs baseline: 5.0609x; 2.6638x over previous
//
#include <hip/hip_runtime.h>
#include <hip/hip_bf16.h>

// Decoder (EGNN) on MI355X. pos==0 identity => stage-2/pos/counts dead.
// ROUND 4: revert to multi-dispatch (cached loads); fuse per-layer.
//   k_scancnt (LDS-atomic count + scan -> off, fill=0)   [1 block]
//   k_bucket  (ecol CSR fill + wfrag blocks 0-3 + g GEMM blocks 4-7)
//   k_preA    (An = (nf@Wn+bn)@eW1[0], Ag = g@eW1[0]; layer-0 separability)
//   k_pre1    (materialize h, A1, A2bf)
//   4x k_layer: 256 blocks x 4 nodes x 16 batches. Wave = node: edge loop
//     (A2 gather from L2, silu, MFMA vs wfrag, silu) -> agg in regs -> AGL
//     in LDS -> node MLP + LN + next-layer A (or output head) with 4x4 reg
//     tiles. P array, items/ioff, and 5 dispatches+gaps eliminated vs the
//     356us baseline. A1/A2 double-buffered across layers (cross-block dep
//     crosses kernel boundary only).

namespace {

constexpr int kE = 32768, kLat = 128;

typedef __attribute__((ext_vector_type(8))) short short8;   // 8 bf16
typedef __attribute__((ext_vector_type(4))) float floatx4;

__device__ __forceinline__ unsigned short f2bf(float f){   // RNE
  union { float f; unsigned int u; } v; v.f = f;
  unsigned int r = v.u + 0x7fffu + ((v.u >> 16) & 1u);
  return (unsigned short)(r >> 16);
}
__device__ __forceinline__ unsigned int packbf(float a, float b){
  return ((unsigned int)f2bf(b) << 16) | (unsigned int)f2bf(a);
}
__device__ __forceinline__ unsigned int pack2f(float a, float b){ // fast half-up
  unsigned int ua = __float_as_uint(a) + 0x8000u;
  unsigned int ub = __float_as_uint(b) + 0x8000u;
  return __builtin_amdgcn_perm(ub, ua, 0x07060302);
}
__device__ __forceinline__ float bflo(unsigned int u){
  union { unsigned int u; float f; } v; v.u = u << 16; return v.f;
}
__device__ __forceinline__ float bfhi(unsigned int u){
  union { unsigned int u; float f; } v; v.u = u & 0xffff0000u; return v.f;
}
__device__ __forceinline__ float silu2(float x){   // 2 trans + 3 alu
  float u = __builtin_amdgcn_exp2f(-1.44269504f * x);
  return x * __builtin_amdgcn_rcpf(1.0f + u);
}

// ---- shared GEMM helpers (64-row tiles, stride-68 transposed activations) --
__device__ __forceinline__ void stage16k(float* Wl, const float* src, int tid){
  const float4* p = (const float4*)src;
  float4* d = (float4*)Wl;
  d[tid]       = p[tid];
  d[tid + 256] = p[tid + 256];
  d[tid + 512] = p[tid + 512];
  d[tid + 768] = p[tid + 768];
}
__device__ __forceinline__ void xtwrite(float* XTl, int j0, int r0,
                                        const float v[4][4]){
  #pragma unroll
  for (int j = 0; j < 4; j++){
    float4 t = { v[0][j], v[1][j], v[2][j], v[3][j] };
    *(float4*)(XTl + (j0 + j)*68 + r0) = t;
  }
}
__device__ __forceinline__ void gemm64(const float* Wl, const float* XTl,
                                       int j0, int r0, float acc[4][4]){
  #pragma unroll 4
  for (int k = 0; k < 64; k++){
    float4 w = *(const float4*)(Wl + k*64 + j0);
    float4 x = *(const float4*)(XTl + k*68 + r0);
    float xv[4] = { x.x, x.y, x.z, x.w };
    float wv[4] = { w.x, w.y, w.z, w.w };
    #pragma unroll
    for (int i = 0; i < 4; i++)
      #pragma unroll
      for (int j = 0; j < 4; j++)
        acc[i][j] += xv[i]*wv[j];
  }
}

// ---- CSR: count (LDS atomics) + scan, one block --------------------------
__global__ void k_scancnt(const int* ei, int* off, int* fill){
  __shared__ int s0[1024];
  __shared__ int s1[1024];
  int t = threadIdx.x;
  s0[t] = 0; fill[t] = 0;
  __syncthreads();
  #pragma unroll
  for (int i = 0; i < 32; i++) atomicAdd(&s0[ei[i*1024 + t]], 1);
  __syncthreads();
  int c = s0[t];
  int* src = s0; int* dst = s1;
  for (int o = 1; o < 1024; o <<= 1){
    int v = src[t] + ((t >= o) ? src[t-o] : 0);
    dst[t] = v; __syncthreads();
    int* tmp = src; src = dst; dst = tmp;
  }
  int inc = src[t];
  off[t] = inc - c;
  if (t == 1023) off[1024] = inc;
}

// ---- bucket + wfrag (blocks 0-3) + g GEMM (blocks 4-7) ---------------------
__global__ void k_bucket(const int* ei, const int* off, int* fill, int* ecol,
                         const float* eW2, unsigned short* wfragE,
                         const float* z, const float* Wg, const float* bg,
                         float* g){
  int e = blockIdx.x*256 + threadIdx.x;
  int r = ei[e];
  int s = atomicAdd(&fill[r], 1);
  ecol[off[r] + s] = ei[kE + e];
  if (blockIdx.x < 4){
    int l = blockIdx.x;
    for (int i = threadIdx.x; i < 4096; i += 256){
      int f = i >> 9, lane = (i >> 3) & 63, j8 = i & 7;
      int jt = f >> 1, ks = f & 1;
      int k = ks*32 + (lane >> 4)*8 + j8;
      int j = jt*16 + (lane & 15);
      wfragE[l*4096 + i] = f2bf(eW2[l*4096 + k*64 + j]);
    }
  } else if (blockIdx.x < 8){
    int b = (blockIdx.x - 4)*4 + (threadIdx.x >> 6);
    int j = threadIdx.x & 63;
    float acc = bg[j];
    for (int k = 0; k < kLat; k++) acc += z[b*kLat + k] * Wg[k*64 + j];
    g[b*64 + j] = acc;
  }
}

// ---- k_preA: An1/An2 = (nf@Wn+bn)@eW1[0] (blocks 0-63); Ag (block 64) -----
__global__ __launch_bounds__(256, 1) void k_preA(const float* nf, const float* Wn,
      const float* bn, const float* g, const float* eW1, const float* eb1,
      float* An1, float* An2, float* Ag1, float* Ag2){
  __shared__ __align__(16) float W0[4096];
  __shared__ __align__(16) float W1[4096];
  __shared__ __align__(16) float HR[16*68];
  int tid = threadIdx.x;
  if (blockIdx.x == 64){
    int bb = tid >> 4, j0 = (tid & 15)*4;
    float a1[4] = {0.f,0.f,0.f,0.f}, a2[4] = {0.f,0.f,0.f,0.f};
    for (int k = 0; k < 64; k++){
      float gk = g[bb*64 + k];
      float4 w1 = *(const float4*)(eW1 + k*64 + j0);
      float4 w2 = *(const float4*)(eW1 + 4096 + k*64 + j0);
      a1[0] += gk*w1.x; a1[1] += gk*w1.y; a1[2] += gk*w1.z; a1[3] += gk*w1.w;
      a2[0] += gk*w2.x; a2[1] += gk*w2.y; a2[2] += gk*w2.z; a2[3] += gk*w2.w;
    }
    float4 o1 = { a1[0], a1[1], a1[2], a1[3] };
    float4 o2 = { a2[0], a2[1], a2[2], a2[3] };
    *(float4*)(Ag1 + bb*64 + j0) = o1;
    *(float4*)(Ag2 + bb*64 + j0) = o2;
    return;
  }
  {
    const float4* e1a = (const float4*)(eW1);
    const float4* e1b = (const float4*)(eW1 + 4096);
    for (int i = tid; i < 1024; i += 256){
      ((float4*)W0)[i] = e1a[i]; ((float4*)W1)[i] = e1b[i];
    }
  }
  int rl = tid >> 4, c = tid & 15, j0 = c*4;
  int n = blockIdx.x*16 + rl;
  float f0 = nf[n*3], f1 = nf[n*3+1], f2 = nf[n*3+2];
  float4 hv;
  hv.x = f0*Wn[j0+0] + f1*Wn[64+j0+0] + f2*Wn[128+j0+0] + bn[j0+0];
  hv.y = f0*Wn[j0+1] + f1*Wn[64+j0+1] + f2*Wn[128+j0+1] + bn[j0+1];
  hv.z = f0*Wn[j0+2] + f1*Wn[64+j0+2] + f2*Wn[128+j0+2] + bn[j0+2];
  hv.w = f0*Wn[j0+3] + f1*Wn[64+j0+3] + f2*Wn[128+j0+3] + bn[j0+3];
  *(float4*)(HR + rl*68 + j0) = hv;
  __syncthreads();
  float4 b1 = *(const float4*)(eb1 + j0);
  float a1[4] = { b1.x, b1.y, b1.z, b1.w };
  float a2[4] = { 0.f, 0.f, 0.f, 0.f };
  #pragma unroll 8
  for (int k = 0; k < 64; k++){
    float hk = HR[rl*68 + k];
    float4 w1 = *(const float4*)(W0 + k*64 + j0);
    float4 w2 = *(const float4*)(W1 + k*64 + j0);
    a1[0] += hk*w1.x; a1[1] += hk*w1.y; a1[2] += hk*w1.z; a1[3] += hk*w1.w;
    a2[0] += hk*w2.x; a2[1] += hk*w2.y; a2[2] += hk*w2.z; a2[3] += hk*w2.w;
  }
  float4 o1 = { a1[0], a1[1], a1[2], a1[3] };
  float4 o2 = { a2[0], a2[1], a2[2], a2[3] };
  *(float4*)(An1 + n*64 + j0) = o1;
  *(float4*)(An2 + n*64 + j0) = o2;
}

// ---- k_pre1: materialize h = nf@Wn+bn+g, A1 = An1+Ag1, A2 = bf16(An2+Ag2) --
__global__ __launch_bounds__(256, 1) void k_pre1(const float* nf, const float* Wn,
      const float* bn, const float* g, const float* An1, const float* An2,
      const float* Ag1, const float* Ag2, float* h, float* A1,
      unsigned short* A2){
  int idx = blockIdx.x*256 + threadIdx.x;
  int row = idx >> 4;          // n*16 + bb
  int j0  = (idx & 15) * 4;
  int n = row >> 4, bb = row & 15;
  float4 a1 = *(const float4*)(An1 + n*64 + j0);
  float4 g1 = *(const float4*)(Ag1 + bb*64 + j0);
  a1.x += g1.x; a1.y += g1.y; a1.z += g1.z; a1.w += g1.w;
  *(float4*)(A1 + row*64 + j0) = a1;
  float4 a2 = *(const float4*)(An2 + n*64 + j0);
  float4 g2 = *(const float4*)(Ag2 + bb*64 + j0);
  a2.x += g2.x; a2.y += g2.y; a2.z += g2.z; a2.w += g2.w;
  uint2 pk; pk.x = packbf(a2.x, a2.y); pk.y = packbf(a2.z, a2.w);
  *(uint2*)(A2 + row*64 + j0) = pk;
  float f0 = nf[n*3], f1 = nf[n*3+1], f2 = nf[n*3+2];
  float4 w0 = *(const float4*)(Wn + j0);
  float4 w1 = *(const float4*)(Wn + 64 + j0);
  float4 w2 = *(const float4*)(Wn + 128 + j0);
  float4 bv = *(const float4*)(bn + j0);
  float4 gv = *(const float4*)(g + bb*64 + j0);
  float4 hv;
  hv.x = f0*w0.x + f1*w1.x + f2*w2.x + bv.x + gv.x;
  hv.y = f0*w0.y + f1*w1.y + f2*w2.y + bv.y + gv.y;
  hv.z = f0*w0.z + f1*w1.z + f2*w2.z + bv.z + gv.z;
  hv.w = f0*w0.w + f1*w1.w + f2*w2.w + bv.w + gv.w;
  *(float4*)(h + (bb*1024 + n)*64 + j0) = hv;
}

// ---- k_layer: fused edge + node MLP + LN (+ next-A | head) -----------------
// 256 blocks x 256 thr. Block = 4 nodes x 16 batches (64 rows). Wave = node.
template <bool LAST>
__global__ __launch_bounds__(256) void k_layer(int l,
      const float* A1r, const unsigned short* A2r,
      float* A1w, unsigned short* A2w,
      float* h, const unsigned short* wfragE, const float* eb2,
      const int* off, const int* ecol,
      const float* nW1, const float* nb1_, const float* nW2, const float* nb2_,
      const float* lng_, const float* lnb_, const float* eW1, const float* eb1_,
      const float* oW1, const float* ob1_, const float* oW2, const float* ob2_,
      float* out){
  __shared__ __align__(16) float W[4096];
  __shared__ __align__(16) float XT[64*68];
  __shared__ __align__(16) float AGL[64*68];
  __shared__ float W2o[192];
  __shared__ float ob2s[4];
  int tid = threadIdx.x, bid = blockIdx.x;
  int n0 = bid * 4;
  int lane = tid & 63, wv = tid >> 6, m = lane & 15, quad = lane >> 4;

  // ---------------- edge phase: wave wv owns node n0+wv ----------------
  {
    int nd = n0 + wv;
    short8 wf[8];
    #pragma unroll
    for (int f = 0; f < 8; f++)
      wf[f] = *(const short8*)(wfragE + l*4096 + f*512 + lane*8);
    floatx4 dini[4], agg[4];
    #pragma unroll
    for (int jt = 0; jt < 4; jt++){
      dini[jt] = *(const floatx4*)(eb2 + l*64 + jt*16 + quad*4);
      agg[jt] = (floatx4){0.f,0.f,0.f,0.f};
    }
    int e0 = off[nd], e1 = off[nd+1];
    if (e0 < e1){
      float4 a1[4];
      #pragma unroll
      for (int ks = 0; ks < 2; ks++){
        a1[ks*2+0] = *(const float4*)(A1r + (nd<<10) + (m<<6) + ks*32 + quad*8);
        a1[ks*2+1] = *(const float4*)(A1r + (nd<<10) + (m<<6) + ks*32 + quad*8 + 4);
      }
      int c0 = ecol[e0];
      uint4 p0 = *(const uint4*)(A2r + ((c0<<4)+m)*64 + quad*8);
      uint4 p1 = *(const uint4*)(A2r + ((c0<<4)+m)*64 + 32 + quad*8);
      for (int e = e0; e < e1; e++){
        uint4 c_0 = p0, c_1 = p1;
        if (e + 1 < e1){
          int cn = ecol[e+1];
          p0 = *(const uint4*)(A2r + ((cn<<4)+m)*64 + quad*8);
          p1 = *(const uint4*)(A2r + ((cn<<4)+m)*64 + 32 + quad*8);
        }
        short8 bfr[2];
        #pragma unroll
        for (int ks = 0; ks < 2; ks++){
          uint4 a2r = (ks == 0) ? c_0 : c_1;
          float4 x0 = a1[ks*2+0];
          float4 x1 = a1[ks*2+1];
          float v0 = silu2(x0.x + bflo(a2r.x));
          float v1 = silu2(x0.y + bfhi(a2r.x));
          float v2 = silu2(x0.z + bflo(a2r.y));
          float v3 = silu2(x0.w + bfhi(a2r.y));
          float v4 = silu2(x1.x + bflo(a2r.z));
          float v5 = silu2(x1.y + bfhi(a2r.z));
          float v6 = silu2(x1.z + bflo(a2r.w));
          float v7 = silu2(x1.w + bfhi(a2r.w));
          union { uint4 u; short8 s; } bu;
          bu.u.x = pack2f(v0, v1); bu.u.y = pack2f(v2, v3);
          bu.u.z = pack2f(v4, v5); bu.u.w = pack2f(v6, v7);
          bfr[ks] = bu.s;
        }
        #pragma unroll
        for (int jt = 0; jt < 4; jt++){
          floatx4 d = dini[jt];
          d = __builtin_amdgcn_mfma_f32_16x16x32_bf16(wf[jt*2+0], bfr[0], d, 0, 0, 0);
          d = __builtin_amdgcn_mfma_f32_16x16x32_bf16(wf[jt*2+1], bfr[1], d, 0, 0, 0);
          floatx4 a = agg[jt];
          a.x += silu2(d.x); a.y += silu2(d.y);
          a.z += silu2(d.z); a.w += silu2(d.w);
          agg[jt] = a;
        }
      }
    }
    // agg -> AGL (transposed: AGL[col][row]); rows rr = wv*16 + m
    #pragma unroll
    for (int jt = 0; jt < 4; jt++){
      #pragma unroll
      for (int i = 0; i < 4; i++)
        AGL[(jt*16 + quad*4 + i)*68 + wv*16 + m] = agg[jt][i];
    }
  }

  // ---------------- post: 64 rows = (node q, batch bb), 4x4 reg tiles --
  int c = tid & 15, gq = tid >> 4;
  int j0 = c*4, r0 = gq*4;

  stage16k(W, nW1 + l*8192, tid);            // W := nW1lo
  float hold[4][4];
  #pragma unroll
  for (int i = 0; i < 4; i++){
    int rr = r0 + i;
    int n = n0 + (rr >> 4), bb = rr & 15;
    float4 v = *(const float4*)(h + (bb*1024 + n)*64 + j0);
    hold[i][0]=v.x; hold[i][1]=v.y; hold[i][2]=v.z; hold[i][3]=v.w;
  }
  xtwrite(XT, j0, r0, hold);
  float acc[4][4];
  { float4 b1 = *(const float4*)(nb1_ + l*64 + j0);
    float bv[4] = { b1.x, b1.y, b1.z, b1.w };
    #pragma unroll
    for (int i = 0; i < 4; i++)
      #pragma unroll
      for (int j = 0; j < 4; j++) acc[i][j] = bv[j]; }
  __syncthreads();                            // edge done; W/XT/AGL ready
  gemm64(W, XT, j0, r0, acc);                 // t += h @ nW1lo
  __syncthreads();
  stage16k(W, nW1 + l*8192 + 4096, tid);      // W := nW1hi
  __syncthreads();
  gemm64(W, AGL, j0, r0, acc);                // t += agg @ nW1hi
  #pragma unroll
  for (int i = 0; i < 4; i++)
    #pragma unroll
    for (int j = 0; j < 4; j++) acc[i][j] = silu2(acc[i][j]);
  __syncthreads();
  stage16k(W, nW2 + l*4096, tid);             // W := nW2
  xtwrite(XT, j0, r0, acc);
  float u[4][4];
  { float4 b2 = *(const float4*)(nb2_ + l*64 + j0);
    float bv[4] = { b2.x, b2.y, b2.z, b2.w };
    #pragma unroll
    for (int i = 0; i < 4; i++)
      #pragma unroll
      for (int j = 0; j < 4; j++) u[i][j] = bv[j]; }
  __syncthreads();
  gemm64(W, XT, j0, r0, u);                   // u = t @ nW2 + nb2
  // residual + LayerNorm (reduce across the 16 c-lanes)
  float4 lgv = *(const float4*)(lng_ + l*64 + j0);
  float4 lbv = *(const float4*)(lnb_ + l*64 + j0);
  float hn[4][4];
  #pragma unroll
  for (int i = 0; i < 4; i++){
    float hv[4];
    #pragma unroll
    for (int j = 0; j < 4; j++) hv[j] = hold[i][j] + u[i][j];
    float s1 = hv[0]+hv[1]+hv[2]+hv[3];
    float s2 = hv[0]*hv[0]+hv[1]*hv[1]+hv[2]*hv[2]+hv[3]*hv[3];
    s1 += __shfl_xor(s1, 1, 64); s1 += __shfl_xor(s1, 2, 64);
    s1 += __shfl_xor(s1, 4, 64); s1 += __shfl_xor(s1, 8, 64);
    s2 += __shfl_xor(s2, 1, 64); s2 += __shfl_xor(s2, 2, 64);
    s2 += __shfl_xor(s2, 4, 64); s2 += __shfl_xor(s2, 8, 64);
    float mu  = s1 * (1.0f/64.0f);
    float var = s2 * (1.0f/64.0f) - mu*mu;
    float rs  = rsqrtf(var + 1e-5f);
    hn[i][0] = (hv[0]-mu)*rs*lgv.x + lbv.x;
    hn[i][1] = (hv[1]-mu)*rs*lgv.y + lbv.y;
    hn[i][2] = (hv[2]-mu)*rs*lgv.z + lbv.z;
    hn[i][3] = (hv[3]-mu)*rs*lgv.w + lbv.w;
  }

  if (!LAST){
    #pragma unroll
    for (int i = 0; i < 4; i++){
      int rr = r0 + i;
      int n = n0 + (rr >> 4), bb = rr & 15;
      float4 v = { hn[i][0], hn[i][1], hn[i][2], hn[i][3] };
      *(float4*)(h + (bb*1024 + n)*64 + j0) = v;
    }
    __syncthreads();
    stage16k(W, eW1 + (l+1)*8256, tid);       // W := eW1lo(l+1)
    xtwrite(XT, j0, r0, hn);
    float a1r[4][4];
    { float4 b1 = *(const float4*)(eb1_ + (l+1)*64 + j0);
      float bv[4] = { b1.x, b1.y, b1.z, b1.w };
      #pragma unroll
      for (int i = 0; i < 4; i++)
        #pragma unroll
        for (int j = 0; j < 4; j++) a1r[i][j] = bv[j]; }
    __syncthreads();
    gemm64(W, XT, j0, r0, a1r);               // A1 = hn @ eW1lo + eb1
    __syncthreads();
    stage16k(W, eW1 + (l+1)*8256 + 4096, tid);// W := eW1hi(l+1)
    float a2r[4][4];
    #pragma unroll
    for (int i = 0; i < 4; i++)
      #pragma unroll
      for (int j = 0; j < 4; j++) a2r[i][j] = 0.f;
    __syncthreads();
    gemm64(W, XT, j0, r0, a2r);               // A2 = hn @ eW1hi
    #pragma unroll
    for (int i = 0; i < 4; i++){
      int rr = r0 + i;
      int n = n0 + (rr >> 4), bb = rr & 15;
      int tb = (n*16 + bb)*64 + j0;
      float4 o1 = { a1r[i][0], a1r[i][1], a1r[i][2], a1r[i][3] };
      *(float4*)(A1w + tb) = o1;
      uint2 pk; pk.x = packbf(a2r[i][0], a2r[i][1]);
      pk.y = packbf(a2r[i][2], a2r[i][3]);
      *(uint2*)(A2w + tb) = pk;
    }
  } else {
    __syncthreads();
    stage16k(W, oW1, tid);                    // W := oW1
    if (tid < 192) W2o[tid] = oW2[tid];
    if (tid < 3)   ob2s[tid] = ob2_[tid];
    xtwrite(XT, j0, r0, hn);
    __syncthreads();
    float tr[4][4];
    { float4 b1 = *(const float4*)(ob1_ + j0);
      float bv[4] = { b1.x, b1.y, b1.z, b1.w };
      #pragma unroll
      for (int i = 0; i < 4; i++)
        #pragma unroll
        for (int j = 0; j < 4; j++) tr[i][j] = bv[j]; }
    gemm64(W, XT, j0, r0, tr);                // t = hn @ oW1 + ob1
    #pragma unroll
    for (int i = 0; i < 4; i++)
      #pragma unroll
      for (int j = 0; j < 4; j++) tr[i][j] = fmaxf(tr[i][j], 0.f);
    float po[4][3];
    #pragma unroll
    for (int i = 0; i < 4; i++){ po[i][0]=0.f; po[i][1]=0.f; po[i][2]=0.f; }
    #pragma unroll
    for (int j = 0; j < 4; j++){
      float w0 = W2o[(j0+j)*3 + 0];
      float w1 = W2o[(j0+j)*3 + 1];
      float w2 = W2o[(j0+j)*3 + 2];
      #pragma unroll
      for (int i = 0; i < 4; i++){
        po[i][0] += tr[i][j]*w0;
        po[i][1] += tr[i][j]*w1;
        po[i][2] += tr[i][j]*w2;
      }
    }
    #pragma unroll
    for (int i = 0; i < 4; i++)
      #pragma unroll
      for (int uu = 0; uu < 3; uu++){
        float v = po[i][uu];
        v += __shfl_xor(v, 1, 64); v += __shfl_xor(v, 2, 64);
        v += __shfl_xor(v, 4, 64); v += __shfl_xor(v, 8, 64);
        po[i][uu] = v;
      }
    if (c == 0){
      #pragma unroll
      for (int i = 0; i < 4; i++){
        int rr = r0 + i;
        int n = n0 + (rr >> 4), bb = rr & 15;
        out[bb*3072 + n*3 + 0] = po[i][0] + ob2s[0];
        out[bb*3072 + n*3 + 1] = po[i][1] + ob2s[1];
        out[bb*3072 + n*3 + 2] = po[i][2] + ob2s[2];
      }
    }
  }
}

} // namespace

extern "C" void kernel_launch(void* const* d_in, const int* in_sizes, int n_in,
                              void* d_out, int out_size, void* d_ws, size_t ws_size,
                              hipStream_t stream){
  const float* z   = (const float*)d_in[0];
  const int*   ei  = (const int*)d_in[1];
  const float* nf  = (const float*)d_in[2];
  const float* Wg  = (const float*)d_in[3];  const float* bg  = (const float*)d_in[4];
  const float* Wn  = (const float*)d_in[5];  const float* bn  = (const float*)d_in[6];
  const float* eW1 = (const float*)d_in[7];  const float* eb1 = (const float*)d_in[8];
  const float* eW2 = (const float*)d_in[9];  const float* eb2 = (const float*)d_in[10];
  const float* nW1 = (const float*)d_in[14]; const float* nb1 = (const float*)d_in[15];
  const float* nW2 = (const float*)d_in[16]; const float* nb2 = (const float*)d_in[17];
  const float* lng = (const float*)d_in[18]; const float* lnb = (const float*)d_in[19];
  const float* oW1 = (const float*)d_in[20]; const float* ob1 = (const float*)d_in[21];
  const float* oW2 = (const float*)d_in[22]; const float* ob2 = (const float*)d_in[23];

  float* W      = (float*)d_ws;
  float* h      = W;                                   // 1,048,576 f
  float* A1a    = W + 1048576;                         // 1,048,576 f
  float* A1b    = W + 2097152;                         // 1,048,576 f
  unsigned short* A2a    = (unsigned short*)(W + 3145728); // 1,048,576 bf16
  unsigned short* A2b    = (unsigned short*)(W + 3670016); // 1,048,576 bf16
  unsigned short* wfragE = (unsigned short*)(W + 4194304); // 16,384 bf16
  float* g      = W + 4202496;                         // 1,024 f
  float* An1    = W + 4203520;                         // 65,536 f
  float* An2    = W + 4269056;                         // 65,536 f
  float* Ag1    = W + 4334592;                         // 1,024 f
  float* Ag2    = W + 4335616;                         // 1,024 f
  int*   off    = (int*)(W + 4336640);                 // 1,025
  int*   fill   = off + 1025;                          // 1,024
  int*   ecol   = fill + 1024;                         // 32,768

  k_scancnt<<<1, 1024, 0, stream>>>(ei, off, fill);
  k_bucket <<<128, 256, 0, stream>>>(ei, off, fill, ecol, eW2, wfragE, z, Wg, bg, g);
  k_preA   <<<65,  256, 0, stream>>>(nf, Wn, bn, g, eW1, eb1, An1, An2, Ag1, Ag2);
  k_pre1   <<<1024,256, 0, stream>>>(nf, Wn, bn, g, An1, An2, Ag1, Ag2, h, A1a, A2a);

  for (int l = 0; l < 4; l++){
    const float* A1r = (l & 1) ? A1b : A1a;
    const unsigned short* A2r = (l & 1) ? A2b : A2a;
    float* A1w = (l & 1) ? A1a : A1b;
    unsigned short* A2w = (l & 1) ? A2a : A2b;
    if (l < 3)
      k_layer<false><<<256, 256, 0, stream>>>(l, A1r, A2r, A1w, A2w, h, wfragE,
            eb2, off, ecol, nW1, nb1, nW2, nb2, lng, lnb, eW1, eb1,
            oW1, ob1, oW2, ob2, (float*)d_out);
    else
      k_layer<true> <<<256, 256, 0, stream>>>(l, A1r, A2r, A1w, A2w, h, wfragE,
            eb2, off, ecol, nW1, nb1, nW2, nb2, lng, lnb, eW1, eb1,
            oW1, ob1, oW2, ob2, (float*)d_out);
  }
}

// Round 6
// 335.052 us; speedup vs baseline: 5.0788x; 1.0036x over previous
//
#include <hip/hip_runtime.h>
#include <hip/hip_bf16.h>

// Decoder (EGNN) on MI355X. pos==0 identity => stage-2/pos/counts dead.
// ROUND 5: attack k_layer occupancy (was 1 block/CU, 8.7% occ, 60us).
//   512 blocks x 2 nodes x 16 batches (32 rows). Post GEMMs keep 4x4 reg
//   tiles (2B/FMA LDS floor) on threads 0-127; threads 128-255 ping-pong
//   stage the NEXT weight buffer (Wa/Wb) during each GEMM. Edge phase: all
//   4 waves (2 waves/node, stride-2 edges -> per-wave edges ~16, tail
//   halved), partial aggs merged via LDS atomicAdd (ds_add_f32).
//   LDS ~51KB -> 2 blocks/CU co-resident: edge (VALU/trans) of one block
//   overlaps LDS-bound post of the other.
//   Also: g folded into k_scancnt, An/Ag folded into k_bucket (8->7 disp).

namespace {

constexpr int kE = 32768, kLat = 128;

typedef __attribute__((ext_vector_type(8))) short short8;   // 8 bf16
typedef __attribute__((ext_vector_type(4))) float floatx4;

__device__ __forceinline__ unsigned short f2bf(float f){   // RNE
  union { float f; unsigned int u; } v; v.f = f;
  unsigned int r = v.u + 0x7fffu + ((v.u >> 16) & 1u);
  return (unsigned short)(r >> 16);
}
__device__ __forceinline__ unsigned int packbf(float a, float b){
  return ((unsigned int)f2bf(b) << 16) | (unsigned int)f2bf(a);
}
__device__ __forceinline__ unsigned int pack2f(float a, float b){ // fast half-up
  unsigned int ua = __float_as_uint(a) + 0x8000u;
  unsigned int ub = __float_as_uint(b) + 0x8000u;
  return __builtin_amdgcn_perm(ub, ua, 0x07060302);
}
__device__ __forceinline__ float bflo(unsigned int u){
  union { unsigned int u; float f; } v; v.u = u << 16; return v.f;
}
__device__ __forceinline__ float bfhi(unsigned int u){
  union { unsigned int u; float f; } v; v.u = u & 0xffff0000u; return v.f;
}
__device__ __forceinline__ float silu2(float x){   // 2 trans + 3 alu
  float u = __builtin_amdgcn_exp2f(-1.44269504f * x);
  return x * __builtin_amdgcn_rcpf(1.0f + u);
}

// stage 16KB weight block with the UPPER 128 threads (u = tid-128)
__device__ __forceinline__ void stageU(float* Wl, const float* src, int u){
  const float4* p = (const float4*)src;
  float4* d = (float4*)Wl;
  #pragma unroll
  for (int q = 0; q < 8; q++) d[u + q*128] = p[u + q*128];
}
// 32-row GEMM, X transposed [64 feat][32 rows + pad4] stride 36
__device__ __forceinline__ void gemm32(const float* Wl, const float* Xl,
                                       int j0, int r0, float acc[4][4]){
  #pragma unroll 4
  for (int k = 0; k < 64; k++){
    float4 w = *(const float4*)(Wl + k*64 + j0);
    float4 x = *(const float4*)(Xl + k*36 + r0);
    float xv[4] = { x.x, x.y, x.z, x.w };
    float wv[4] = { w.x, w.y, w.z, w.w };
    #pragma unroll
    for (int i = 0; i < 4; i++)
      #pragma unroll
      for (int j = 0; j < 4; j++)
        acc[i][j] += xv[i]*wv[j];
  }
}

// ---- CSR count+scan (1 block) + g = z@Wg+bg ------------------------------
__global__ void k_scancnt(const int* ei, int* off, int* fill,
                          const float* z, const float* Wg, const float* bg,
                          float* g){
  __shared__ int s0[1024];
  __shared__ int s1[1024];
  int t = threadIdx.x;
  s0[t] = 0; fill[t] = 0;
  __syncthreads();
  #pragma unroll
  for (int i = 0; i < 32; i++) atomicAdd(&s0[ei[i*1024 + t]], 1);
  __syncthreads();
  int c = s0[t];
  int* src = s0; int* dst = s1;
  for (int o = 1; o < 1024; o <<= 1){
    int v = src[t] + ((t >= o) ? src[t-o] : 0);
    dst[t] = v; __syncthreads();
    int* tmp = src; src = dst; dst = tmp;
  }
  int inc = src[t];
  off[t] = inc - c;
  if (t == 1023) off[1024] = inc;
  // g GEMM: thread t -> (batch t>>6, col t&63)
  int b = t >> 6, j = t & 63;
  float acc = bg[j];
  for (int k = 0; k < kLat; k++) acc += z[b*kLat + k] * Wg[k*64 + j];
  g[b*64 + j] = acc;
}

// ---- bucket + wfrag (0-3) + An (4-67) + Ag (68) ---------------------------
__global__ void k_bucket(const int* ei, const int* off, int* fill, int* ecol,
                         const float* eW2, unsigned short* wfragE,
                         const float* nf, const float* Wn, const float* bn,
                         const float* eW1, const float* eb1, const float* g,
                         float* An1, float* An2, float* Ag1, float* Ag2){
  __shared__ __align__(16) float W0[4096];
  __shared__ __align__(16) float W1[4096];
  __shared__ __align__(16) float HR[16*68];
  int tid = threadIdx.x, bid = blockIdx.x;
  int e = bid*256 + tid;
  int r = ei[e];
  int s = atomicAdd(&fill[r], 1);
  ecol[off[r] + s] = ei[kE + e];
  if (bid < 4){
    int l = bid;
    for (int i = tid; i < 4096; i += 256){
      int f = i >> 9, lane = (i >> 3) & 63, j8 = i & 7;
      int jt = f >> 1, ks = f & 1;
      int k = ks*32 + (lane >> 4)*8 + j8;
      int j = jt*16 + (lane & 15);
      wfragE[l*4096 + i] = f2bf(eW2[l*4096 + k*64 + j]);
    }
  } else if (bid < 68){               // An = (nf@Wn+bn) @ eW1[0]
    const float4* e1a = (const float4*)(eW1);
    const float4* e1b = (const float4*)(eW1 + 4096);
    for (int i = tid; i < 1024; i += 256){
      ((float4*)W0)[i] = e1a[i]; ((float4*)W1)[i] = e1b[i];
    }
    int rl = tid >> 4, c = tid & 15, j0 = c*4;
    int n = (bid - 4)*16 + rl;
    float f0 = nf[n*3], f1 = nf[n*3+1], f2 = nf[n*3+2];
    float4 hv;
    hv.x = f0*Wn[j0+0] + f1*Wn[64+j0+0] + f2*Wn[128+j0+0] + bn[j0+0];
    hv.y = f0*Wn[j0+1] + f1*Wn[64+j0+1] + f2*Wn[128+j0+1] + bn[j0+1];
    hv.z = f0*Wn[j0+2] + f1*Wn[64+j0+2] + f2*Wn[128+j0+2] + bn[j0+2];
    hv.w = f0*Wn[j0+3] + f1*Wn[64+j0+3] + f2*Wn[128+j0+3] + bn[j0+3];
    *(float4*)(HR + rl*68 + j0) = hv;
    __syncthreads();
    float4 b1 = *(const float4*)(eb1 + j0);
    float a1[4] = { b1.x, b1.y, b1.z, b1.w };
    float a2[4] = { 0.f, 0.f, 0.f, 0.f };
    #pragma unroll 8
    for (int k = 0; k < 64; k++){
      float hk = HR[rl*68 + k];
      float4 w1 = *(const float4*)(W0 + k*64 + j0);
      float4 w2 = *(const float4*)(W1 + k*64 + j0);
      a1[0] += hk*w1.x; a1[1] += hk*w1.y; a1[2] += hk*w1.z; a1[3] += hk*w1.w;
      a2[0] += hk*w2.x; a2[1] += hk*w2.y; a2[2] += hk*w2.z; a2[3] += hk*w2.w;
    }
    float4 o1 = { a1[0], a1[1], a1[2], a1[3] };
    float4 o2 = { a2[0], a2[1], a2[2], a2[3] };
    *(float4*)(An1 + n*64 + j0) = o1;
    *(float4*)(An2 + n*64 + j0) = o2;
  } else if (bid == 68){              // Ag = g @ eW1[0]
    int bb = tid >> 4, j0 = (tid & 15)*4;
    float a1[4] = {0.f,0.f,0.f,0.f}, a2[4] = {0.f,0.f,0.f,0.f};
    for (int k = 0; k < 64; k++){
      float gk = g[bb*64 + k];
      float4 w1 = *(const float4*)(eW1 + k*64 + j0);
      float4 w2 = *(const float4*)(eW1 + 4096 + k*64 + j0);
      a1[0] += gk*w1.x; a1[1] += gk*w1.y; a1[2] += gk*w1.z; a1[3] += gk*w1.w;
      a2[0] += gk*w2.x; a2[1] += gk*w2.y; a2[2] += gk*w2.z; a2[3] += gk*w2.w;
    }
    float4 o1 = { a1[0], a1[1], a1[2], a1[3] };
    float4 o2 = { a2[0], a2[1], a2[2], a2[3] };
    *(float4*)(Ag1 + bb*64 + j0) = o1;
    *(float4*)(Ag2 + bb*64 + j0) = o2;
  }
}

// ---- k_pre1: materialize h = nf@Wn+bn+g, A1 = An1+Ag1, A2 = bf16(An2+Ag2) --
__global__ __launch_bounds__(256, 1) void k_pre1(const float* nf, const float* Wn,
      const float* bn, const float* g, const float* An1, const float* An2,
      const float* Ag1, const float* Ag2, float* h, float* A1,
      unsigned short* A2){
  int idx = blockIdx.x*256 + threadIdx.x;
  int row = idx >> 4;          // n*16 + bb
  int j0  = (idx & 15) * 4;
  int n = row >> 4, bb = row & 15;
  float4 a1 = *(const float4*)(An1 + n*64 + j0);
  float4 g1 = *(const float4*)(Ag1 + bb*64 + j0);
  a1.x += g1.x; a1.y += g1.y; a1.z += g1.z; a1.w += g1.w;
  *(float4*)(A1 + row*64 + j0) = a1;
  float4 a2 = *(const float4*)(An2 + n*64 + j0);
  float4 g2 = *(const float4*)(Ag2 + bb*64 + j0);
  a2.x += g2.x; a2.y += g2.y; a2.z += g2.z; a2.w += g2.w;
  uint2 pk; pk.x = packbf(a2.x, a2.y); pk.y = packbf(a2.z, a2.w);
  *(uint2*)(A2 + row*64 + j0) = pk;
  float f0 = nf[n*3], f1 = nf[n*3+1], f2 = nf[n*3+2];
  float4 w0 = *(const float4*)(Wn + j0);
  float4 w1 = *(const float4*)(Wn + 64 + j0);
  float4 w2 = *(const float4*)(Wn + 128 + j0);
  float4 bv = *(const float4*)(bn + j0);
  float4 gv = *(const float4*)(g + bb*64 + j0);
  float4 hv;
  hv.x = f0*w0.x + f1*w1.x + f2*w2.x + bv.x + gv.x;
  hv.y = f0*w0.y + f1*w1.y + f2*w2.y + bv.y + gv.y;
  hv.z = f0*w0.z + f1*w1.z + f2*w2.z + bv.z + gv.z;
  hv.w = f0*w0.w + f1*w1.w + f2*w2.w + bv.w + gv.w;
  *(float4*)(h + (bb*1024 + n)*64 + j0) = hv;
}

// ---- k_layer: fused edge + node MLP + LN (+ next-A | head) -----------------
// 512 blocks x 256 thr. Block = 2 nodes x 16 batches (32 rows).
// Edge: 4 waves, wave wv -> node n0+(wv>>1), edges stride 2; AGL atomicAdd.
// Post: threads 0-127 gemm (4x4 tiles), threads 128-255 stage next W.
template <bool LAST>
__global__ __launch_bounds__(256) void k_layer(int l,
      const float* A1r, const unsigned short* A2r,
      float* A1w, unsigned short* A2w,
      float* h, const unsigned short* wfragE, const float* eb2,
      const int* off, const int* ecol,
      const float* nW1, const float* nb1_, const float* nW2, const float* nb2_,
      const float* lng_, const float* lnb_, const float* eW1, const float* eb1_,
      const float* oW1, const float* ob1_, const float* oW2, const float* ob2_,
      float* out){
  __shared__ __align__(16) float Wa[4096];
  __shared__ __align__(16) float Wb[4096];
  __shared__ __align__(16) float XT[64*36];
  __shared__ __align__(16) float AGL[64*36];
  __shared__ float W2o[192];
  __shared__ float ob2s[4];
  int tid = threadIdx.x, bid = blockIdx.x;
  int n0 = bid * 2;
  int lane = tid & 63, wv = tid >> 6, m = lane & 15, quad = lane >> 4;

  for (int i = tid; i < 64*36; i += 256) AGL[i] = 0.f;
  __syncthreads();

  // ---------------- edge phase ----------------
  {
    int nd = n0 + (wv >> 1);
    short8 wf[8];
    #pragma unroll
    for (int f = 0; f < 8; f++)
      wf[f] = *(const short8*)(wfragE + l*4096 + f*512 + lane*8);
    floatx4 dini[4], agg[4];
    #pragma unroll
    for (int jt = 0; jt < 4; jt++){
      dini[jt] = *(const floatx4*)(eb2 + l*64 + jt*16 + quad*4);
      agg[jt] = (floatx4){0.f,0.f,0.f,0.f};
    }
    int e0 = off[nd] + (wv & 1), e1 = off[nd+1];
    if (e0 < e1){
      float4 a1[4];
      #pragma unroll
      for (int ks = 0; ks < 2; ks++){
        a1[ks*2+0] = *(const float4*)(A1r + (nd<<10) + (m<<6) + ks*32 + quad*8);
        a1[ks*2+1] = *(const float4*)(A1r + (nd<<10) + (m<<6) + ks*32 + quad*8 + 4);
      }
      int c0 = ecol[e0];
      uint4 p0 = *(const uint4*)(A2r + ((c0<<4)+m)*64 + quad*8);
      uint4 p1 = *(const uint4*)(A2r + ((c0<<4)+m)*64 + 32 + quad*8);
      for (int e = e0; e < e1; e += 2){
        uint4 c_0 = p0, c_1 = p1;
        if (e + 2 < e1){
          int cn = ecol[e+2];
          p0 = *(const uint4*)(A2r + ((cn<<4)+m)*64 + quad*8);
          p1 = *(const uint4*)(A2r + ((cn<<4)+m)*64 + 32 + quad*8);
        }
        short8 bfr[2];
        #pragma unroll
        for (int ks = 0; ks < 2; ks++){
          uint4 a2r = (ks == 0) ? c_0 : c_1;
          float4 x0 = a1[ks*2+0];
          float4 x1 = a1[ks*2+1];
          float v0 = silu2(x0.x + bflo(a2r.x));
          float v1 = silu2(x0.y + bfhi(a2r.x));
          float v2 = silu2(x0.z + bflo(a2r.y));
          float v3 = silu2(x0.w + bfhi(a2r.y));
          float v4 = silu2(x1.x + bflo(a2r.z));
          float v5 = silu2(x1.y + bfhi(a2r.z));
          float v6 = silu2(x1.z + bflo(a2r.w));
          float v7 = silu2(x1.w + bfhi(a2r.w));
          union { uint4 u; short8 s; } bu;
          bu.u.x = pack2f(v0, v1); bu.u.y = pack2f(v2, v3);
          bu.u.z = pack2f(v4, v5); bu.u.w = pack2f(v6, v7);
          bfr[ks] = bu.s;
        }
        #pragma unroll
        for (int jt = 0; jt < 4; jt++){
          floatx4 d = dini[jt];
          d = __builtin_amdgcn_mfma_f32_16x16x32_bf16(wf[jt*2+0], bfr[0], d, 0, 0, 0);
          d = __builtin_amdgcn_mfma_f32_16x16x32_bf16(wf[jt*2+1], bfr[1], d, 0, 0, 0);
          floatx4 a = agg[jt];
          a.x += silu2(d.x); a.y += silu2(d.y);
          a.z += silu2(d.z); a.w += silu2(d.w);
          agg[jt] = a;
        }
      }
    }
    int rloc = (wv >> 1)*16 + m;
    #pragma unroll
    for (int jt = 0; jt < 4; jt++)
      #pragma unroll
      for (int i = 0; i < 4; i++)
        atomicAdd(&AGL[(jt*16 + quad*4 + i)*36 + rloc], agg[jt][i]);
  }

  // ---------------- post: lower 128 gemm, upper 128 stage ----------------
  bool lo = (tid < 128);
  int up = tid - 128;
  int c = tid & 15, gq = tid >> 4;      // gq in 0..7 for lo threads
  int j0 = c*4, r0 = gq*4;

  float hold[4][4];
  float acc[4][4];
  if (lo){
    #pragma unroll
    for (int i = 0; i < 4; i++){
      int rr = r0 + i;
      int nd2 = n0 + (rr >> 4), bb = rr & 15;
      float4 v = *(const float4*)(h + (bb*1024 + nd2)*64 + j0);
      hold[i][0]=v.x; hold[i][1]=v.y; hold[i][2]=v.z; hold[i][3]=v.w;
    }
    #pragma unroll
    for (int j = 0; j < 4; j++){
      float4 t = { hold[0][j], hold[1][j], hold[2][j], hold[3][j] };
      *(float4*)(XT + (j0 + j)*36 + r0) = t;
    }
    float4 b1 = *(const float4*)(nb1_ + l*64 + j0);
    float bv[4] = { b1.x, b1.y, b1.z, b1.w };
    #pragma unroll
    for (int i = 0; i < 4; i++)
      #pragma unroll
      for (int j = 0; j < 4; j++) acc[i][j] = bv[j];
  } else {
    stageU(Wa, nW1 + l*8192, up);
  }
  __syncthreads();                       // AGL + XT + Wa ready
  if (lo) gemm32(Wa, XT, j0, r0, acc);   // t += h @ nW1lo
  else    stageU(Wb, nW1 + l*8192 + 4096, up);
  __syncthreads();
  if (lo){
    gemm32(Wb, AGL, j0, r0, acc);        // t += agg @ nW1hi
    #pragma unroll
    for (int i = 0; i < 4; i++)
      #pragma unroll
      for (int j = 0; j < 4; j++) acc[i][j] = silu2(acc[i][j]);
    #pragma unroll
    for (int j = 0; j < 4; j++){
      float4 t = { acc[0][j], acc[1][j], acc[2][j], acc[3][j] };
      *(float4*)(XT + (j0 + j)*36 + r0) = t;
    }
  } else {
    stageU(Wa, nW2 + l*4096, up);
  }
  __syncthreads();
  float hn[4][4];
  if (lo){
    float u4[4][4];
    float4 b2 = *(const float4*)(nb2_ + l*64 + j0);
    float bv[4] = { b2.x, b2.y, b2.z, b2.w };
    #pragma unroll
    for (int i = 0; i < 4; i++)
      #pragma unroll
      for (int j = 0; j < 4; j++) u4[i][j] = bv[j];
    gemm32(Wa, XT, j0, r0, u4);          // u = t @ nW2 + nb2
    float4 lgv = *(const float4*)(lng_ + l*64 + j0);
    float4 lbv = *(const float4*)(lnb_ + l*64 + j0);
    #pragma unroll
    for (int i = 0; i < 4; i++){
      float hv[4];
      #pragma unroll
      for (int j = 0; j < 4; j++) hv[j] = hold[i][j] + u4[i][j];
      float s1 = hv[0]+hv[1]+hv[2]+hv[3];
      float s2 = hv[0]*hv[0]+hv[1]*hv[1]+hv[2]*hv[2]+hv[3]*hv[3];
      s1 += __shfl_xor(s1, 1, 64); s1 += __shfl_xor(s1, 2, 64);
      s1 += __shfl_xor(s1, 4, 64); s1 += __shfl_xor(s1, 8, 64);
      s2 += __shfl_xor(s2, 1, 64); s2 += __shfl_xor(s2, 2, 64);
      s2 += __shfl_xor(s2, 4, 64); s2 += __shfl_xor(s2, 8, 64);
      float mu  = s1 * (1.0f/64.0f);
      float var = s2 * (1.0f/64.0f) - mu*mu;
      float rs  = rsqrtf(var + 1e-5f);
      hn[i][0] = (hv[0]-mu)*rs*lgv.x + lbv.x;
      hn[i][1] = (hv[1]-mu)*rs*lgv.y + lbv.y;
      hn[i][2] = (hv[2]-mu)*rs*lgv.z + lbv.z;
      hn[i][3] = (hv[3]-mu)*rs*lgv.w + lbv.w;
    }
    if (!LAST){
      #pragma unroll
      for (int i = 0; i < 4; i++){
        int rr = r0 + i;
        int nd2 = n0 + (rr >> 4), bb = rr & 15;
        float4 v = { hn[i][0], hn[i][1], hn[i][2], hn[i][3] };
        *(float4*)(h + (bb*1024 + nd2)*64 + j0) = v;
      }
    }
    // hn -> AGL (AGL free after gemm2)
    #pragma unroll
    for (int j = 0; j < 4; j++){
      float4 t = { hn[0][j], hn[1][j], hn[2][j], hn[3][j] };
      *(float4*)(AGL + (j0 + j)*36 + r0) = t;
    }
  } else {
    if (!LAST){
      stageU(Wb, eW1 + (l+1)*8256, up);
    } else {
      stageU(Wb, oW1, up);
      W2o[up] = oW2[up];
      if (up < 64) W2o[128 + up] = oW2[128 + up];
      if (up < 3)  ob2s[up] = ob2_[up];
    }
  }
  __syncthreads();
  if (!LAST){
    float a1r[4][4];
    if (lo){
      float4 b1 = *(const float4*)(eb1_ + (l+1)*64 + j0);
      float bv[4] = { b1.x, b1.y, b1.z, b1.w };
      #pragma unroll
      for (int i = 0; i < 4; i++)
        #pragma unroll
        for (int j = 0; j < 4; j++) a1r[i][j] = bv[j];
      gemm32(Wb, AGL, j0, r0, a1r);      // A1 = hn @ eW1lo + eb1
    } else {
      stageU(Wa, eW1 + (l+1)*8256 + 4096, up);
    }
    __syncthreads();
    if (lo){
      float a2r[4][4];
      #pragma unroll
      for (int i = 0; i < 4; i++)
        #pragma unroll
        for (int j = 0; j < 4; j++) a2r[i][j] = 0.f;
      gemm32(Wa, AGL, j0, r0, a2r);      // A2 = hn @ eW1hi
      #pragma unroll
      for (int i = 0; i < 4; i++){
        int rr = r0 + i;
        int nd2 = n0 + (rr >> 4), bb = rr & 15;
        int tb = (nd2*16 + bb)*64 + j0;
        float4 o1 = { a1r[i][0], a1r[i][1], a1r[i][2], a1r[i][3] };
        *(float4*)(A1w + tb) = o1;
        uint2 pk; pk.x = packbf(a2r[i][0], a2r[i][1]);
        pk.y = packbf(a2r[i][2], a2r[i][3]);
        *(uint2*)(A2w + tb) = pk;
      }
    }
  } else {
    if (lo){
      float tr[4][4];
      float4 b1 = *(const float4*)(ob1_ + j0);
      float bv[4] = { b1.x, b1.y, b1.z, b1.w };
      #pragma unroll
      for (int i = 0; i < 4; i++)
        #pragma unroll
        for (int j = 0; j < 4; j++) tr[i][j] = bv[j];
      gemm32(Wb, AGL, j0, r0, tr);       // t = hn @ oW1 + ob1
      #pragma unroll
      for (int i = 0; i < 4; i++)
        #pragma unroll
        for (int j = 0; j < 4; j++) tr[i][j] = fmaxf(tr[i][j], 0.f);
      float po[4][3];
      #pragma unroll
      for (int i = 0; i < 4; i++){ po[i][0]=0.f; po[i][1]=0.f; po[i][2]=0.f; }
      #pragma unroll
      for (int j = 0; j < 4; j++){
        float w0 = W2o[(j0+j)*3 + 0];
        float w1 = W2o[(j0+j)*3 + 1];
        float w2 = W2o[(j0+j)*3 + 2];
        #pragma unroll
        for (int i = 0; i < 4; i++){
          po[i][0] += tr[i][j]*w0;
          po[i][1] += tr[i][j]*w1;
          po[i][2] += tr[i][j]*w2;
        }
      }
      #pragma unroll
      for (int i = 0; i < 4; i++)
        #pragma unroll
        for (int uu = 0; uu < 3; uu++){
          float v = po[i][uu];
          v += __shfl_xor(v, 1, 64); v += __shfl_xor(v, 2, 64);
          v += __shfl_xor(v, 4, 64); v += __shfl_xor(v, 8, 64);
          po[i][uu] = v;
        }
      if (c == 0){
        #pragma unroll
        for (int i = 0; i < 4; i++){
          int rr = r0 + i;
          int nd2 = n0 + (rr >> 4), bb = rr & 15;
          out[bb*3072 + nd2*3 + 0] = po[i][0] + ob2s[0];
          out[bb*3072 + nd2*3 + 1] = po[i][1] + ob2s[1];
          out[bb*3072 + nd2*3 + 2] = po[i][2] + ob2s[2];
        }
      }
    }
  }
}

} // namespace

extern "C" void kernel_launch(void* const* d_in, const int* in_sizes, int n_in,
                              void* d_out, int out_size, void* d_ws, size_t ws_size,
                              hipStream_t stream){
  const float* z   = (const float*)d_in[0];
  const int*   ei  = (const int*)d_in[1];
  const float* nf  = (const float*)d_in[2];
  const float* Wg  = (const float*)d_in[3];  const float* bg  = (const float*)d_in[4];
  const float* Wn  = (const float*)d_in[5];  const float* bn  = (const float*)d_in[6];
  const float* eW1 = (const float*)d_in[7];  const float* eb1 = (const float*)d_in[8];
  const float* eW2 = (const float*)d_in[9];  const float* eb2 = (const float*)d_in[10];
  const float* nW1 = (const float*)d_in[14]; const float* nb1 = (const float*)d_in[15];
  const float* nW2 = (const float*)d_in[16]; const float* nb2 = (const float*)d_in[17];
  const float* lng = (const float*)d_in[18]; const float* lnb = (const float*)d_in[19];
  const float* oW1 = (const float*)d_in[20]; const float* ob1 = (const float*)d_in[21];
  const float* oW2 = (const float*)d_in[22]; const float* ob2 = (const float*)d_in[23];

  float* W      = (float*)d_ws;
  float* h      = W;                                   // 1,048,576 f
  float* A1a    = W + 1048576;                         // 1,048,576 f
  float* A1b    = W + 2097152;                         // 1,048,576 f
  unsigned short* A2a    = (unsigned short*)(W + 3145728); // 1,048,576 bf16
  unsigned short* A2b    = (unsigned short*)(W + 3670016); // 1,048,576 bf16
  unsigned short* wfragE = (unsigned short*)(W + 4194304); // 16,384 bf16
  float* g      = W + 4202496;                         // 1,024 f
  float* An1    = W + 4203520;                         // 65,536 f
  float* An2    = W + 4269056;                         // 65,536 f
  float* Ag1    = W + 4334592;                         // 1,024 f
  float* Ag2    = W + 4335616;                         // 1,024 f
  int*   off    = (int*)(W + 4336640);                 // 1,025
  int*   fill   = off + 1025;                          // 1,024
  int*   ecol   = fill + 1024;                         // 32,768

  k_scancnt<<<1, 1024, 0, stream>>>(ei, off, fill, z, Wg, bg, g);
  k_bucket <<<128, 256, 0, stream>>>(ei, off, fill, ecol, eW2, wfragE,
                                     nf, Wn, bn, eW1, eb1, g, An1, An2, Ag1, Ag2);
  k_pre1   <<<1024,256, 0, stream>>>(nf, Wn, bn, g, An1, An2, Ag1, Ag2, h, A1a, A2a);

  for (int l = 0; l < 4; l++){
    const float* A1r = (l & 1) ? A1b : A1a;
    const unsigned short* A2r = (l & 1) ? A2b : A2a;
    float* A1w = (l & 1) ? A1a : A1b;
    unsigned short* A2w = (l & 1) ? A2a : A2b;
    if (l < 3)
      k_layer<false><<<512, 256, 0, stream>>>(l, A1r, A2r, A1w, A2w, h, wfragE,
            eb2, off, ecol, nW1, nb1, nW2, nb2, lng, lnb, eW1, eb1,
            oW1, ob1, oW2, ob2, (float*)d_out);
    else
      k_layer<true> <<<512, 256, 0, stream>>>(l, A1r, A2r, A1w, A2w, h, wfragE,
            eb2, off, ecol, nW1, nb1, nW2, nb2, lng, lnb, eW1, eb1,
            oW1, ob1, oW2, ob2, (float*)d_out);
  }
}